// Round 1
// 1584.714 us; speedup vs baseline: 1.0157x; 1.0157x over previous
//
#include <hip/hip_runtime.h>
#include <cfloat>
#include <cmath>

#define NN 20000
#define EE 640000
#define DIN 1546
#define KIN 1568   // DIN padded to multiple of 32
#define DH 128
#define DFF 512
#define NL 2
#define NPROJ 768   // q|k|v|r|hi|hj packed columns
#define ALB 2048    // attn_logits blocks (one final atomic each)

typedef unsigned short ushort_t;
typedef __attribute__((ext_vector_type(8))) short short8;
typedef __attribute__((ext_vector_type(8))) unsigned short ushort8;
typedef __attribute__((ext_vector_type(4))) float floatx4;

__device__ inline ushort_t f2bf(float f) {
  unsigned u = __float_as_uint(f);
  unsigned r = (u + 0x7FFF + ((u >> 16) & 1)) >> 16;
  return (ushort_t)r;
}
__device__ inline float bflo(unsigned u) { return __uint_as_float(u << 16); }
__device__ inline float bfhi(unsigned u) { return __uint_as_float(u & 0xFFFF0000u); }

// ---------------------------------------------------------------------------
// bf16 MFMA GEMM: C[M x N] = act(A[M x K] @ Bt[N x K]^T + bias)
// A, Bt bf16 (ushort). K % 32 == 0, lda/ldb % 8 == 0. Grid: (ceil(M/128), N/128)
// with Bt zero-padded to gridDim.y*128 rows. Stores guarded by row<M, col<Nstore.
// LDS layout [kq][row][8] with plane stride 1032 elems (bank-uniform).
// act: 0 none, 1 relu, 2 leaky(0.01).  out_bf16: 1 -> ushort C, 0 -> float C.
// ---------------------------------------------------------------------------
__global__ __launch_bounds__(256) void gemm_bf16(
    const ushort_t* __restrict__ A, int lda,
    const ushort_t* __restrict__ Bt, int ldb,
    const float* __restrict__ bias, void* __restrict__ Cv, int ldc,
    int M, int Nstore, int K, int act, int out_bf16)
{
  __shared__ ushort_t As[4 * 1032];
  __shared__ ushort_t Bs[4 * 1032];
  const int tid = threadIdx.x;
  const int wave = tid >> 6, lane = tid & 63;
  const int bm = blockIdx.x * 128, bn = blockIdx.y * 128;
  const int wm = (wave >> 1) * 64, wn = (wave & 1) * 64;
  const int frow = lane & 15, kq = lane >> 4;

  floatx4 acc[4][4];
  #pragma unroll
  for (int i = 0; i < 4; ++i)
    #pragma unroll
    for (int j = 0; j < 4; ++j) acc[i][j] = (floatx4){0.f, 0.f, 0.f, 0.f};

  // staging: thread covers (row = tid>>2 [+64], kchunk = tid&3)
  const int srow = tid >> 2, skc = tid & 3;
  const int ar0 = min(bm + srow, M - 1);
  const int ar1 = min(bm + srow + 64, M - 1);
  const ushort_t* Ap0 = A + (size_t)ar0 * lda + skc * 8;
  const ushort_t* Ap1 = A + (size_t)ar1 * lda + skc * 8;
  const ushort_t* Bp0 = Bt + (size_t)(bn + srow) * ldb + skc * 8;
  const ushort_t* Bp1 = Bt + (size_t)(bn + srow + 64) * ldb + skc * 8;
  ushort_t* Aw0 = As + skc * 1032 + srow * 8;
  ushort_t* Aw1 = As + skc * 1032 + (srow + 64) * 8;
  ushort_t* Bw0 = Bs + skc * 1032 + srow * 8;
  ushort_t* Bw1 = Bs + skc * 1032 + (srow + 64) * 8;

  for (int k0 = 0; k0 < K; k0 += 32) {
    ushort8 a0 = *(const ushort8*)Ap0; Ap0 += 32;
    ushort8 a1 = *(const ushort8*)Ap1; Ap1 += 32;
    ushort8 b0 = *(const ushort8*)Bp0; Bp0 += 32;
    ushort8 b1 = *(const ushort8*)Bp1; Bp1 += 32;
    __syncthreads();
    *(ushort8*)Aw0 = a0; *(ushort8*)Aw1 = a1;
    *(ushort8*)Bw0 = b0; *(ushort8*)Bw1 = b1;
    __syncthreads();
    short8 af[4], bf[4];
    #pragma unroll
    for (int i = 0; i < 4; ++i)
      af[i] = *(const short8*)(As + kq * 1032 + (wm + i * 16 + frow) * 8);
    #pragma unroll
    for (int j = 0; j < 4; ++j)
      bf[j] = *(const short8*)(Bs + kq * 1032 + (wn + j * 16 + frow) * 8);
    #pragma unroll
    for (int i = 0; i < 4; ++i)
      #pragma unroll
      for (int j = 0; j < 4; ++j)
        acc[i][j] = __builtin_amdgcn_mfma_f32_16x16x32_bf16(af[i], bf[j], acc[i][j], 0, 0, 0);
  }

  const int rq = (lane >> 4) * 4;
  #pragma unroll
  for (int j = 0; j < 4; ++j) {
    int col = bn + wn + j * 16 + frow;
    if (col >= Nstore) continue;
    float bb = bias ? bias[col] : 0.f;
    #pragma unroll
    for (int i = 0; i < 4; ++i) {
      #pragma unroll
      for (int r = 0; r < 4; ++r) {
        int row = bm + wm + i * 16 + rq + r;
        if (row >= M) continue;
        float v = acc[i][j][r] + bb;
        if (act == 1) v = fmaxf(v, 0.f);
        else if (act == 2) v = v > 0.f ? v : 0.01f * v;
        if (out_bf16) ((ushort_t*)Cv)[(size_t)row * ldc + col] = f2bf(v);
        else          ((float*)Cv)[(size_t)row * ldc + col] = v;
      }
    }
  }
}

// ---------------------------------------------------------------------------
// Pack / convert kernels (run per call; weights are restored every launch)
// ---------------------------------------------------------------------------
__global__ void convert_x_kernel(const float* __restrict__ x, ushort_t* __restrict__ xb) {
  int c = blockIdx.x * 256 + threadIdx.x;
  int row = blockIdx.y;
  if (c >= KIN) return;
  xb[(size_t)row * KIN + c] = (c < DIN) ? f2bf(x[(size_t)row * DIN + c]) : (ushort_t)0;
}

__global__ void pack6_kernel(const float* __restrict__ Wq, const float* __restrict__ Wk,
                             const float* __restrict__ Wv, const float* __restrict__ Wr,
                             const float* __restrict__ Whi, const float* __restrict__ Whj,
                             ushort_t* __restrict__ Wt6) {
  int k = blockIdx.x * 256 + threadIdx.x;
  int n = blockIdx.y;
  if (k >= KIN) return;
  const float* W[6] = {Wq, Wk, Wv, Wr, Whi, Whj};
  int which = n >> 7, col = n & 127;
  float v = (k < DIN) ? W[which][(size_t)k * DH + col] : 0.f;
  Wt6[(size_t)n * KIN + k] = f2bf(v);
}

// dst[n][k] (stride Kp) = bf16(src[k*Nsrc + n]) with zero padding
__global__ void pack_bt_kernel(const float* __restrict__ src, ushort_t* __restrict__ dst,
                               int Nsrc, int Ksrc, int Kp) {
  int k = blockIdx.x * 256 + threadIdx.x;
  int n = blockIdx.y;
  if (k >= Kp) return;
  float v = (n < Nsrc && k < Ksrc) ? src[(size_t)k * Nsrc + n] : 0.f;
  dst[(size_t)n * Kp + k] = f2bf(v);
}

__global__ void pack_bias_kernel(const float* __restrict__ bq, const float* __restrict__ bk,
                                 const float* __restrict__ bv, const float* __restrict__ br,
                                 float* __restrict__ out) {
  int n = blockIdx.x * 256 + threadIdx.x;
  if (n >= NPROJ) return;
  int which = n >> 7, c = n & 127;
  float v = 0.f;
  if (which == 0) v = bq[c]; else if (which == 1) v = bk[c];
  else if (which == 2) v = bv[c]; else if (which == 3) v = br[c];
  out[n] = v;
}

// ---------------------------------------------------------------------------
// Weight folding: since x_{l+1} = h_l @ linW + linb is consumed ONLY by the
// next layer's projections (or by lin2W at the end), fold linW into them:
//   x @ W + b  ==  h @ (linW @ W) + (linb @ W + b)
// Combined weights computed in f32 (exact), rounded to bf16 once.
// Pc[n][k] = sum_d W6[d][n] * linW[k][d]   (Bt layout for gemm_bf16, K=DH)
// bc[n]    = b6[n] + sum_d linb[d] * W6[d][n]
// Block: 256 thr = 2 column-groups of 128; each group owns one n.
// ---------------------------------------------------------------------------
__global__ __launch_bounds__(256) void combine6_kernel(
    const float* __restrict__ Wq, const float* __restrict__ Wk,
    const float* __restrict__ Wv, const float* __restrict__ Wr,
    const float* __restrict__ Whi, const float* __restrict__ Whj,
    const float* __restrict__ bq, const float* __restrict__ bk,
    const float* __restrict__ bv, const float* __restrict__ br,
    const float* __restrict__ linW, const float* __restrict__ linb,
    ushort_t* __restrict__ Pc, float* __restrict__ bc)
{
  const int j = threadIdx.x >> 7;      // group 0/1
  const int k = threadIdx.x & 127;
  const int n = blockIdx.x * 2 + j;
  const int which = n >> 7, col = n & 127;
  const float* Ws[6] = {Wq, Wk, Wv, Wr, Whi, Whj};
  const float* W = Ws[which];
  __shared__ float wcol[2][DIN];
  for (int d = k; d < DIN; d += 128)
    wcol[j][d] = W[(size_t)d * DH + col];
  __syncthreads();
  const float* lr = linW + (size_t)k * DIN;
  float acc = 0.f;
  #pragma unroll 4
  for (int d = 0; d < DIN; d += 2) {     // DIN even
    float2 lv = *(const float2*)(lr + d);
    acc = fmaf(wcol[j][d], lv.x, acc);
    acc = fmaf(wcol[j][d + 1], lv.y, acc);
  }
  Pc[(size_t)n * DH + k] = f2bf(acc);
  float bs = 0.f;
  for (int d = k; d < DIN; d += 128) bs += linb[d] * wcol[j][d];
  #pragma unroll
  for (int m = 32; m >= 1; m >>= 1) bs += __shfl_xor(bs, m);
  __shared__ float red[4];
  if ((threadIdx.x & 63) == 0) red[threadIdx.x >> 6] = bs;
  __syncthreads();
  if (k == 0) {
    float b0 = 0.f;
    if (which == 0) b0 = bq[col]; else if (which == 1) b0 = bk[col];
    else if (which == 2) b0 = bv[col]; else if (which == 3) b0 = br[col];
    bc[n] = b0 + red[j * 2] + red[j * 2 + 1];
  }
}

// Pf[c][k] = sum_d linW[k][d] * lin2W[d][c];  bf[c] = lin2b[c] + sum_d linb[d]*lin2W[d][c]
__global__ __launch_bounds__(256) void combine_fin_kernel(
    const float* __restrict__ lin2W, const float* __restrict__ lin2b,
    const float* __restrict__ linW, const float* __restrict__ linb,
    ushort_t* __restrict__ Pf, float* __restrict__ bf_out)
{
  const int j = threadIdx.x >> 7;
  const int k = threadIdx.x & 127;
  const int c = blockIdx.x * 2 + j;
  __shared__ float wcol[2][DIN];
  for (int d = k; d < DIN; d += 128)
    wcol[j][d] = lin2W[(size_t)d * DH + c];
  __syncthreads();
  const float* lr = linW + (size_t)k * DIN;
  float acc = 0.f;
  #pragma unroll 4
  for (int d = 0; d < DIN; d += 2) {
    float2 lv = *(const float2*)(lr + d);
    acc = fmaf(wcol[j][d], lv.x, acc);
    acc = fmaf(wcol[j][d + 1], lv.y, acc);
  }
  Pf[(size_t)c * DH + k] = f2bf(acc);
  float bs = 0.f;
  for (int d = k; d < DIN; d += 128) bs += linb[d] * wcol[j][d];
  #pragma unroll
  for (int m = 32; m >= 1; m >>= 1) bs += __shfl_xor(bs, m);
  __shared__ float red[4];
  if ((threadIdx.x & 63) == 0) red[threadIdx.x >> 6] = bs;
  __syncthreads();
  if (k == 0) bf_out[c] = lin2b[c] + red[j * 2] + red[j * 2 + 1];
}

// ---------------------------------------------------------------------------
// CSR build (once per call; edge_index constant across layers)
// ---------------------------------------------------------------------------
__global__ void hist_kernel(const int* __restrict__ ei, int* __restrict__ counts) {
  int e = blockIdx.x * 256 + threadIdx.x;
  if (e < EE) atomicAdd(&counts[ei[EE + e]], 1);
}

__global__ __launch_bounds__(1024) void scan_kernel(const int* __restrict__ counts,
                                                    int* __restrict__ offsets,
                                                    int* __restrict__ cursor) {
  __shared__ int sums[1024];
  const int t = threadIdx.x;
  const int PER = 20;  // 1024*20 = 20480 >= NN
  int base = t * PER;
  int loc[PER]; int s = 0;
  #pragma unroll
  for (int i = 0; i < PER; ++i) {
    int idx = base + i;
    int c = (idx < NN) ? counts[idx] : 0;
    loc[i] = s; s += c;
  }
  sums[t] = s;
  __syncthreads();
  for (int d = 1; d < 1024; d <<= 1) {
    int v = (t >= d) ? sums[t - d] : 0;
    __syncthreads();
    sums[t] += v;
    __syncthreads();
  }
  int pre = (t > 0) ? sums[t - 1] : 0;
  #pragma unroll
  for (int i = 0; i < PER; ++i) {
    int idx = base + i;
    if (idx < NN) { offsets[idx] = pre + loc[i]; cursor[idx] = pre + loc[i]; }
  }
  if (t == 0) offsets[NN] = sums[1023];
}

__global__ void scatter_kernel(const int* __restrict__ ei, int* __restrict__ cursor,
                               int* __restrict__ csr) {
  int e = blockIdx.x * 256 + threadIdx.x;
  if (e < EE) {
    int p = atomicAdd(&cursor[ei[EE + e]], 1);
    csr[p] = e;
  }
}

// ---------------------------------------------------------------------------
// Attention: global softmax over all E edge logits
// ---------------------------------------------------------------------------
__device__ inline void atomicMaxF(float* addr, float val) {
  if (val >= 0.f) atomicMax((int*)addr, __float_as_int(val));
  else            atomicMin((unsigned int*)addr, __float_as_uint(val));
}

__global__ void init_scalars(float* scal) {
  if (threadIdx.x == 0) { scal[0] = -INFINITY; scal[1] = 0.f; }
}

// s_e[e] = dot(q[dst], k[src]) from packed bf16 qkv. Grid-stride, 2-way
// unrolled; ONE atomicMaxF per block.
__global__ __launch_bounds__(256) void attn_logits(
    const int* __restrict__ ei, const ushort_t* __restrict__ qkv,
    float* __restrict__ s_e, float* __restrict__ scal)
{
  const int tid = threadIdx.x;
  const int l = tid & 31;
  const int ngroups = ALB * 8;
  const int g = blockIdx.x * 8 + (tid >> 5);
  float mx = -FLT_MAX;
  for (int e = g; e < EE; e += 2 * ngroups) {
    const int e2 = e + ngroups;
    const bool has2 = (e2 < EE);
    int src1 = ei[e], dst1 = ei[EE + e];
    int src2 = has2 ? ei[e2] : src1;
    int dst2 = has2 ? ei[EE + e2] : dst1;
    uint2 qu1 = *(const uint2*)(qkv + (size_t)dst1 * NPROJ + l * 4);
    uint2 ku1 = *(const uint2*)(qkv + (size_t)src1 * NPROJ + DH + l * 4);
    uint2 qu2 = *(const uint2*)(qkv + (size_t)dst2 * NPROJ + l * 4);
    uint2 ku2 = *(const uint2*)(qkv + (size_t)src2 * NPROJ + DH + l * 4);
    float d1 = bflo(qu1.x) * bflo(ku1.x) + bfhi(qu1.x) * bfhi(ku1.x)
             + bflo(qu1.y) * bflo(ku1.y) + bfhi(qu1.y) * bfhi(ku1.y);
    float d2 = bflo(qu2.x) * bflo(ku2.x) + bfhi(qu2.x) * bfhi(ku2.x)
             + bflo(qu2.y) * bflo(ku2.y) + bfhi(qu2.y) * bfhi(ku2.y);
    #pragma unroll
    for (int m = 16; m >= 1; m >>= 1) {
      d1 += __shfl_xor(d1, m);
      d2 += __shfl_xor(d2, m);
    }
    if (l == 0) {
      s_e[e] = d1;
      if (has2) s_e[e2] = d2;
    }
    mx = fmaxf(mx, has2 ? fmaxf(d1, d2) : d1);
  }
  mx = fmaxf(mx, __shfl_xor(mx, 32));
  __shared__ float red[4];
  if ((tid & 63) == 0) red[tid >> 6] = mx;
  __syncthreads();
  if (tid == 0)
    atomicMaxF(scal, fmaxf(fmaxf(red[0], red[1]), fmaxf(red[2], red[3])));
}

__global__ __launch_bounds__(256) void exp_sum(
    float* __restrict__ s_e, const float* __restrict__ scal, float* __restrict__ Z)
{
  const int e = blockIdx.x * 256 + threadIdx.x;
  const float mx = scal[0];
  float v = __expf(s_e[e] - mx);
  s_e[e] = v;
  float t = v;
  #pragma unroll
  for (int m = 32; m >= 1; m >>= 1) t += __shfl_xor(t, m);
  __shared__ float red[4];
  if ((threadIdx.x & 63) == 0) red[threadIdx.x >> 6] = t;
  __syncthreads();
  if (threadIdx.x == 0) atomicAdd(Z, red[0] + red[1] + red[2] + red[3]);
}

// ---------------------------------------------------------------------------
// Fused per-dst aggregation: h[i] = r[i] + sum_e p_e * v[src] * gate_e
// ---------------------------------------------------------------------------
__global__ __launch_bounds__(256) void aggregate_kernel(
    const int* __restrict__ ei, const int* __restrict__ offsets,
    const int* __restrict__ csr, const float* __restrict__ s_e,
    const float* __restrict__ scal, const ushort_t* __restrict__ qkv,
    const float* __restrict__ ea, float* __restrict__ h)
{
  const int node = blockIdx.x * 4 + (threadIdx.x >> 6);
  const int lane = threadIdx.x & 63;
  if (node >= NN) return;
  const int off = offsets[node];
  const int deg = offsets[node + 1] - off;
  const float invZ = 1.f / scal[1];
  const ushort_t* bd = qkv + (size_t)node * NPROJ;
  unsigned hjp = *(const unsigned*)(bd + 640 + lane * 2);
  unsigned rp  = *(const unsigned*)(bd + 384 + lane * 2);
  const float hj0 = bflo(hjp), hj1 = bfhi(hjp);
  float a0 = bflo(rp), a1 = bfhi(rp);
  for (int b0 = 0; b0 < deg; b0 += 64) {
    int t = b0 + lane;
    int eL = (t < deg) ? csr[off + t] : 0;
    int sL = (t < deg) ? ei[eL] : 0;
    float pL = (t < deg) ? s_e[eL] * invZ : 0.f;
    int cnt = min(64, deg - b0);
    for (int u = 0; u < cnt; ++u) {
      int e = __shfl(eL, u);
      int src = __shfl(sL, u);
      float p = __shfl(pL, u);
      const ushort_t* bs = qkv + (size_t)src * NPROJ;
      unsigned vv = *(const unsigned*)(bs + 256 + lane * 2);
      unsigned hv = *(const unsigned*)(bs + 512 + lane * 2);
      float2 eav = *(const float2*)(ea + (size_t)e * DH + lane * 2);
      float g0 = 1.f / (1.f + __expf(-(eav.x + bflo(hv) + hj0)));
      float g1 = 1.f / (1.f + __expf(-(eav.y + bfhi(hv) + hj1)));
      a0 = fmaf(p * bflo(vv), g0, a0);
      a1 = fmaf(p * bfhi(vv), g1, a1);
    }
  }
  *(float2*)(h + (size_t)node * DH + lane * 2) = make_float2(a0, a1);
}

// ---------------------------------------------------------------------------
// LayerNorm over rows of 128 (optionally X+X2), writes f32 and/or bf16.
// ---------------------------------------------------------------------------
__global__ __launch_bounds__(256) void ln_kernel(
    const float* __restrict__ X, const float* __restrict__ X2,
    const float* __restrict__ g, const float* __restrict__ b,
    float* __restrict__ Yf, ushort_t* __restrict__ Yb)
{
  int row = blockIdx.x * 4 + (threadIdx.x >> 6);
  int lane = threadIdx.x & 63;
  if (row >= NN) return;
  float2 x = *(const float2*)(X + (size_t)row * DH + lane * 2);
  if (X2) {
    float2 y = *(const float2*)(X2 + (size_t)row * DH + lane * 2);
    x.x += y.x; x.y += y.y;
  }
  float s = x.x + x.y;
  #pragma unroll
  for (int m = 32; m >= 1; m >>= 1) s += __shfl_xor(s, m);
  float mean = s * (1.f / 128.f);
  float dx = x.x - mean, dy = x.y - mean;
  float v = dx * dx + dy * dy;
  #pragma unroll
  for (int m = 32; m >= 1; m >>= 1) v += __shfl_xor(v, m);
  float rstd = rsqrtf(v * (1.f / 128.f) + 1e-5f);
  float2 gg = *(const float2*)(g + lane * 2);
  float2 bb = *(const float2*)(b + lane * 2);
  float o0 = dx * rstd * gg.x + bb.x;
  float o1 = dy * rstd * gg.y + bb.y;
  if (Yf) *(float2*)(Yf + (size_t)row * DH + lane * 2) = make_float2(o0, o1);
  if (Yb) {
    ushort_t* p = Yb + (size_t)row * DH + lane * 2;
    p[0] = f2bf(o0); p[1] = f2bf(o1);
  }
}

// ---------------------------------------------------------------------------
extern "C" void kernel_launch(void* const* d_in, const int* in_sizes, int n_in,
                              void* d_out, int out_size, void* d_ws, size_t ws_size,
                              hipStream_t stream)
{
  const float* x_in  = (const float*)d_in[0];
  const int*   ei    = (const int*)d_in[1];
  const float* ea    = (const float*)d_in[2];
  const float* Wq    = (const float*)d_in[3];
  const float* bq    = (const float*)d_in[4];
  const float* Wk    = (const float*)d_in[5];
  const float* bk    = (const float*)d_in[6];
  const float* Wv    = (const float*)d_in[7];
  const float* bv    = (const float*)d_in[8];
  const float* Wr    = (const float*)d_in[9];
  const float* br    = (const float*)d_in[10];
  const float* Whi   = (const float*)d_in[11];
  const float* Whj   = (const float*)d_in[12];
  const float* W1    = (const float*)d_in[13];
  const float* b1    = (const float*)d_in[14];
  const float* W2    = (const float*)d_in[15];
  const float* b2    = (const float*)d_in[16];
  const float* g1    = (const float*)d_in[17];
  const float* be1   = (const float*)d_in[18];
  const float* g2    = (const float*)d_in[19];
  const float* be2   = (const float*)d_in[20];
  const float* linW  = (const float*)d_in[21];
  const float* linb  = (const float*)d_in[22];
  const float* lin2W = (const float*)d_in[23];
  const float* lin2b = (const float*)d_in[24];
  float* out = (float*)d_out;

  // bump allocator over d_ws (64B aligned)
  char* p = (char*)d_ws;
  auto alloc = [&](size_t bytes) -> void* {
    void* r = (void*)p; p += (bytes + 63) & ~((size_t)63); return r;
  };
  ushort_t* x_bf   = (ushort_t*)alloc((size_t)NN * KIN * 2);
  ushort_t* qkvp   = (ushort_t*)alloc((size_t)NN * NPROJ * 2);
  ushort_t* Wt6    = (ushort_t*)alloc((size_t)NPROJ * KIN * 2);
  ushort_t* W1t    = (ushort_t*)alloc((size_t)DFF * DH * 2);
  ushort_t* W2t    = (ushort_t*)alloc((size_t)DH * DFF * 2);
  ushort_t* Wc6    = (ushort_t*)alloc((size_t)NPROJ * DH * 2);  // folded layer-1 proj
  ushort_t* Wcf    = (ushort_t*)alloc((size_t)DH * DH * 2);     // folded final linear
  float*    bias768= (float*)alloc(NPROJ * 4);
  float*    bc768  = (float*)alloc(NPROJ * 4);
  float*    bcf    = (float*)alloc(DH * 4);
  float*    s_e    = (float*)alloc((size_t)EE * 4);
  float*    scal   = (float*)alloc(64);
  int*      counts = (int*)alloc((size_t)NN * 4);
  int*      offsets= (int*)alloc((size_t)(NN + 1) * 4);
  int*      cursor = (int*)alloc((size_t)NN * 4);
  int*      csr    = (int*)alloc((size_t)EE * 4);
  float*    h      = (float*)alloc((size_t)NN * DH * 4);
  float*    ss     = (float*)alloc((size_t)NN * DH * 4);
  ushort_t* ssbf   = (ushort_t*)alloc((size_t)NN * DH * 2);
  ushort_t* ff1bf  = (ushort_t*)alloc((size_t)NN * DFF * 2);
  float*    ss2    = (float*)alloc((size_t)NN * DH * 4);
  ushort_t* h2bf   = (ushort_t*)alloc((size_t)NN * DH * 2);

  const dim3 blk(256);
  const int MB = (NN + 127) / 128;  // 157

  // --- setup: convert x, build CSR, fold linW into layer-1 / final weights ---
  convert_x_kernel<<<dim3(7, NN), blk, 0, stream>>>(x_in, x_bf);
  hipMemsetAsync(counts, 0, (size_t)NN * 4, stream);
  hist_kernel<<<dim3(EE / 256), blk, 0, stream>>>(ei, counts);
  scan_kernel<<<dim3(1), dim3(1024), 0, stream>>>(counts, offsets, cursor);
  scatter_kernel<<<dim3(EE / 256), blk, 0, stream>>>(ei, cursor, csr);

  const size_t wo1 = (size_t)DIN * DH;  // layer-1 weight offset
  combine6_kernel<<<dim3(NPROJ / 2), blk, 0, stream>>>(
      Wq + wo1, Wk + wo1, Wv + wo1, Wr + wo1, Whi + wo1, Whj + wo1,
      bq + DH, bk + DH, bv + DH, br + DH, linW, linb, Wc6, bc768);
  combine_fin_kernel<<<dim3(DH / 2), blk, 0, stream>>>(
      lin2W, lin2b, linW, linb, Wcf, bcf);

  for (int l = 0; l < NL; ++l) {
    pack_bt_kernel<<<dim3(1, DFF), blk, 0, stream>>>(W1 + (size_t)l * DH * DFF, W1t, DFF, DH, DH);
    pack_bt_kernel<<<dim3(2, DH), blk, 0, stream>>>(W2 + (size_t)l * DFF * DH, W2t, DH, DFF, DFF);

    if (l == 0) {
      // layer 0: full-width projection from input x
      pack6_kernel<<<dim3(7, NPROJ), blk, 0, stream>>>(
          Wq, Wk, Wv, Wr, Whi, Whj, Wt6);
      pack_bias_kernel<<<dim3(3), blk, 0, stream>>>(bq, bk, bv, br, bias768);
      gemm_bf16<<<dim3(MB, 6), blk, 0, stream>>>(
          x_bf, KIN, Wt6, KIN, bias768, qkvp, NPROJ, NN, NPROJ, KIN, 0, 1);
    } else {
      // layer 1: folded projection directly from h2 (K = 128)
      gemm_bf16<<<dim3(MB, 6), blk, 0, stream>>>(
          h2bf, DH, Wc6, DH, bc768, qkvp, NPROJ, NN, NPROJ, DH, 0, 1);
    }

    // global-softmax attention + aggregation
    init_scalars<<<1, 64, 0, stream>>>(scal);
    attn_logits<<<dim3(ALB), blk, 0, stream>>>(ei, qkvp, s_e, scal);
    exp_sum<<<dim3(EE / 256), blk, 0, stream>>>(s_e, scal, scal + 1);
    aggregate_kernel<<<dim3(NN / 4), blk, 0, stream>>>(
        ei, offsets, csr, s_e, scal, qkvp, ea, h);

    // FFMLP with pre-norm residual
    ln_kernel<<<dim3(NN / 4), blk, 0, stream>>>(h, nullptr, g1 + (size_t)l * DH, be1 + (size_t)l * DH, ss, ssbf);
    gemm_bf16<<<dim3(MB, 4), blk, 0, stream>>>(
        ssbf, DH, W1t, DH, b1 + (size_t)l * DFF, ff1bf, DFF, NN, DFF, DH, 1, 1);
    gemm_bf16<<<dim3(MB, 1), blk, 0, stream>>>(
        ff1bf, DFF, W2t, DFF, b2 + (size_t)l * DH, ss2, DH, NN, DH, DFF, 0, 0);
    ln_kernel<<<dim3(NN / 4), blk, 0, stream>>>(ss, ss2, g2 + (size_t)l * DH, be2 + (size_t)l * DH, nullptr, h2bf);
    // NOTE: no 128->1546 lin GEMM — linW is folded into the next consumer.
  }

  // final: folded (linW @ lin2W) 128 -> 128 + leaky_relu, fp32 out
  gemm_bf16<<<dim3(MB, 1), blk, 0, stream>>>(
      h2bf, DH, Wcf, DH, bcf, out, DH, NN, DH, DH, 2, 0);
}

// Round 4
// 1583.567 us; speedup vs baseline: 1.0164x; 1.0007x over previous
//
#include <hip/hip_runtime.h>
#include <cfloat>
#include <cmath>

#define NN 20000
#define EE 640000
#define DIN 1546
#define KIN 1568   // DIN padded to multiple of 32
#define DH 128
#define DFF 512
#define NL 2
#define NPROJ 768   // q|k|v|r|hi|hj packed columns
#define ALB 2048    // attn_logits blocks (one final atomic each)

typedef unsigned short ushort_t;
typedef __attribute__((ext_vector_type(8))) short short8;
typedef __attribute__((ext_vector_type(8))) unsigned short ushort8;
typedef __attribute__((ext_vector_type(4))) float floatx4;

__device__ inline ushort_t f2bf(float f) {
  unsigned u = __float_as_uint(f);
  unsigned r = (u + 0x7FFF + ((u >> 16) & 1)) >> 16;
  return (ushort_t)r;
}
__device__ inline float bflo(unsigned u) { return __uint_as_float(u << 16); }
__device__ inline float bfhi(unsigned u) { return __uint_as_float(u & 0xFFFF0000u); }

// ---------------------------------------------------------------------------
// bf16 MFMA GEMM: C[M x N] = act(A[M x K] @ Bt[N x K]^T + bias)
// A, Bt bf16 (ushort). K % 32 == 0, lda/ldb % 8 == 0. Grid: (ceil(M/128), N/128)
// with Bt having exactly gridDim.y*128 rows. Stores guarded by row<M, col<Nstore.
// LDS layout [kq][row][8] with plane stride 1032 elems (bank-uniform).
// Reg-staged (harness-proven R1 structure).
// act: 0 none, 1 relu, 2 leaky(0.01).  out_bf16: 1 -> ushort C, 0 -> float C.
// ---------------------------------------------------------------------------
__global__ __launch_bounds__(256) void gemm_bf16(
    const ushort_t* __restrict__ A, int lda,
    const ushort_t* __restrict__ Bt, int ldb,
    const float* __restrict__ bias, void* __restrict__ Cv, int ldc,
    int M, int Nstore, int K, int act, int out_bf16)
{
  __shared__ ushort_t As[4 * 1032];
  __shared__ ushort_t Bs[4 * 1032];
  const int tid = threadIdx.x;
  const int wave = tid >> 6, lane = tid & 63;
  const int bm = blockIdx.x * 128, bn = blockIdx.y * 128;
  const int wm = (wave >> 1) * 64, wn = (wave & 1) * 64;
  const int frow = lane & 15, kq = lane >> 4;

  floatx4 acc[4][4];
  #pragma unroll
  for (int i = 0; i < 4; ++i)
    #pragma unroll
    for (int j = 0; j < 4; ++j) acc[i][j] = (floatx4){0.f, 0.f, 0.f, 0.f};

  // staging: thread covers (row = tid>>2 [+64], kchunk = tid&3)
  const int srow = tid >> 2, skc = tid & 3;
  const int ar0 = min(bm + srow, M - 1);
  const int ar1 = min(bm + srow + 64, M - 1);
  const ushort_t* Ap0 = A + (size_t)ar0 * lda + skc * 8;
  const ushort_t* Ap1 = A + (size_t)ar1 * lda + skc * 8;
  const ushort_t* Bp0 = Bt + (size_t)(bn + srow) * ldb + skc * 8;
  const ushort_t* Bp1 = Bt + (size_t)(bn + srow + 64) * ldb + skc * 8;
  ushort_t* Aw0 = As + skc * 1032 + srow * 8;
  ushort_t* Aw1 = As + skc * 1032 + (srow + 64) * 8;
  ushort_t* Bw0 = Bs + skc * 1032 + srow * 8;
  ushort_t* Bw1 = Bs + skc * 1032 + (srow + 64) * 8;

  for (int k0 = 0; k0 < K; k0 += 32) {
    ushort8 a0 = *(const ushort8*)Ap0; Ap0 += 32;
    ushort8 a1 = *(const ushort8*)Ap1; Ap1 += 32;
    ushort8 b0 = *(const ushort8*)Bp0; Bp0 += 32;
    ushort8 b1 = *(const ushort8*)Bp1; Bp1 += 32;
    __syncthreads();
    *(ushort8*)Aw0 = a0; *(ushort8*)Aw1 = a1;
    *(ushort8*)Bw0 = b0; *(ushort8*)Bw1 = b1;
    __syncthreads();
    short8 af[4], bfv[4];
    #pragma unroll
    for (int i = 0; i < 4; ++i)
      af[i] = *(const short8*)(As + kq * 1032 + (wm + i * 16 + frow) * 8);
    #pragma unroll
    for (int j = 0; j < 4; ++j)
      bfv[j] = *(const short8*)(Bs + kq * 1032 + (wn + j * 16 + frow) * 8);
    #pragma unroll
    for (int i = 0; i < 4; ++i)
      #pragma unroll
      for (int j = 0; j < 4; ++j)
        acc[i][j] = __builtin_amdgcn_mfma_f32_16x16x32_bf16(af[i], bfv[j], acc[i][j], 0, 0, 0);
  }

  const int rq = (lane >> 4) * 4;
  #pragma unroll
  for (int j = 0; j < 4; ++j) {
    int col = bn + wn + j * 16 + frow;
    if (col >= Nstore) continue;
    float bb = bias ? bias[col] : 0.f;
    #pragma unroll
    for (int i = 0; i < 4; ++i) {
      #pragma unroll
      for (int r = 0; r < 4; ++r) {
        int row = bm + wm + i * 16 + rq + r;
        if (row >= M) continue;
        float v = acc[i][j][r] + bb;
        if (act == 1) v = fmaxf(v, 0.f);
        else if (act == 2) v = v > 0.f ? v : 0.01f * v;
        if (out_bf16) ((ushort_t*)Cv)[(size_t)row * ldc + col] = f2bf(v);
        else          ((float*)Cv)[(size_t)row * ldc + col] = v;
      }
    }
  }
}

// ---------------------------------------------------------------------------
// Pack / convert kernels
// ---------------------------------------------------------------------------
// grid-stride ushort8 conversion: 20000x1546 f32 -> 20000x1568 bf16 (zero pad)
__global__ __launch_bounds__(256) void convert_x_kernel(
    const float* __restrict__ x, ushort_t* __restrict__ xb)
{
  const unsigned CPR = KIN / 8;  // 196 chunks per row
  unsigned gid = blockIdx.x * 256 + threadIdx.x;
  if (gid >= (unsigned)NN * CPR) return;
  unsigned row = gid / CPR;
  unsigned c8 = (gid - row * CPR) * 8;
  const float* xr = x + (size_t)row * DIN;
  ushort8 o;
  #pragma unroll
  for (int j = 0; j < 8; ++j)
    o[j] = (c8 + j < DIN) ? f2bf(xr[c8 + j]) : (ushort_t)0;
  *(ushort8*)(xb + (size_t)row * KIN + c8) = o;
}

// tiled-transpose pack of the 6 projection weights (coalesced both sides)
__global__ __launch_bounds__(256) void pack6t_kernel(
    const float* __restrict__ Wq, const float* __restrict__ Wk,
    const float* __restrict__ Wv, const float* __restrict__ Wr,
    const float* __restrict__ Whi, const float* __restrict__ Whj,
    ushort_t* __restrict__ Wt6)
{
  __shared__ float tile[32][33];
  const int k0 = blockIdx.x * 32;   // 49 blocks -> 1568
  const int n0 = blockIdx.y * 32;   // 24 blocks -> 768
  const float* Ws[6] = {Wq, Wk, Wv, Wr, Whi, Whj};
  const float* W = Ws[n0 >> 7];
  const int c0 = n0 & 127;
  const int tc = threadIdx.x & 31, tr = threadIdx.x >> 5;
  #pragma unroll
  for (int r = tr; r < 32; r += 8) {
    int k = k0 + r;
    tile[r][tc] = (k < DIN) ? W[(size_t)k * DH + c0 + tc] : 0.f;
  }
  __syncthreads();
  #pragma unroll
  for (int n = tr; n < 32; n += 8)
    Wt6[(size_t)(n0 + n) * KIN + k0 + tc] = f2bf(tile[tc][n]);
}

// dst[n][k] (stride Kp) = bf16(src[k*Nsrc + n]) with zero padding
__global__ void pack_bt_kernel(const float* __restrict__ src, ushort_t* __restrict__ dst,
                               int Nsrc, int Ksrc, int Kp) {
  int k = blockIdx.x * 256 + threadIdx.x;
  int n = blockIdx.y;
  if (k >= Kp) return;
  float v = (n < Nsrc && k < Ksrc) ? src[(size_t)k * Nsrc + n] : 0.f;
  dst[(size_t)n * Kp + k] = f2bf(v);
}

__global__ void pack_bias_kernel(const float* __restrict__ bq, const float* __restrict__ bk,
                                 const float* __restrict__ bv, const float* __restrict__ br,
                                 float* __restrict__ out) {
  int n = blockIdx.x * 256 + threadIdx.x;
  if (n >= NPROJ) return;
  int which = n >> 7, c = n & 127;
  float v = 0.f;
  if (which == 0) v = bq[c]; else if (which == 1) v = bk[c];
  else if (which == 2) v = bv[c]; else if (which == 3) v = br[c];
  out[n] = v;
}

// ---------------------------------------------------------------------------
// Weight folding: x @ W + b == h @ (linW @ W) + (linb @ W + b)
// Combined in f32 (exact), rounded to bf16 once.
// ---------------------------------------------------------------------------
__global__ __launch_bounds__(256) void combine6_kernel(
    const float* __restrict__ Wq, const float* __restrict__ Wk,
    const float* __restrict__ Wv, const float* __restrict__ Wr,
    const float* __restrict__ Whi, const float* __restrict__ Whj,
    const float* __restrict__ bq, const float* __restrict__ bk,
    const float* __restrict__ bv, const float* __restrict__ br,
    const float* __restrict__ linW, const float* __restrict__ linb,
    ushort_t* __restrict__ Pc, float* __restrict__ bc)
{
  const int j = threadIdx.x >> 7;
  const int k = threadIdx.x & 127;
  const int n = blockIdx.x * 2 + j;
  const int which = n >> 7, col = n & 127;
  const float* Ws[6] = {Wq, Wk, Wv, Wr, Whi, Whj};
  const float* W = Ws[which];
  __shared__ float wcol[2][DIN];
  for (int d = k; d < DIN; d += 128)
    wcol[j][d] = W[(size_t)d * DH + col];
  __syncthreads();
  const float* lr = linW + (size_t)k * DIN;
  float acc = 0.f;
  #pragma unroll 4
  for (int d = 0; d < DIN; d += 2) {
    float2 lv = *(const float2*)(lr + d);
    acc = fmaf(wcol[j][d], lv.x, acc);
    acc = fmaf(wcol[j][d + 1], lv.y, acc);
  }
  Pc[(size_t)n * DH + k] = f2bf(acc);
  float bs = 0.f;
  for (int d = k; d < DIN; d += 128) bs += linb[d] * wcol[j][d];
  #pragma unroll
  for (int m = 32; m >= 1; m >>= 1) bs += __shfl_xor(bs, m);
  __shared__ float red[4];
  if ((threadIdx.x & 63) == 0) red[threadIdx.x >> 6] = bs;
  __syncthreads();
  if (k == 0) {
    float b0 = 0.f;
    if (which == 0) b0 = bq[col]; else if (which == 1) b0 = bk[col];
    else if (which == 2) b0 = bv[col]; else if (which == 3) b0 = br[col];
    bc[n] = b0 + red[j * 2] + red[j * 2 + 1];
  }
}

__global__ __launch_bounds__(256) void combine_fin_kernel(
    const float* __restrict__ lin2W, const float* __restrict__ lin2b,
    const float* __restrict__ linW, const float* __restrict__ linb,
    ushort_t* __restrict__ Pf, float* __restrict__ bf_out)
{
  const int j = threadIdx.x >> 7;
  const int k = threadIdx.x & 127;
  const int c = blockIdx.x * 2 + j;
  __shared__ float wcol[2][DIN];
  for (int d = k; d < DIN; d += 128)
    wcol[j][d] = lin2W[(size_t)d * DH + c];
  __syncthreads();
  const float* lr = linW + (size_t)k * DIN;
  float acc = 0.f;
  #pragma unroll 4
  for (int d = 0; d < DIN; d += 2) {
    float2 lv = *(const float2*)(lr + d);
    acc = fmaf(wcol[j][d], lv.x, acc);
    acc = fmaf(wcol[j][d + 1], lv.y, acc);
  }
  Pf[(size_t)c * DH + k] = f2bf(acc);
  float bs = 0.f;
  for (int d = k; d < DIN; d += 128) bs += linb[d] * wcol[j][d];
  #pragma unroll
  for (int m = 32; m >= 1; m >>= 1) bs += __shfl_xor(bs, m);
  __shared__ float red[4];
  if ((threadIdx.x & 63) == 0) red[threadIdx.x >> 6] = bs;
  __syncthreads();
  if (k == 0) bf_out[c] = lin2b[c] + red[j * 2] + red[j * 2 + 1];
}

// ---------------------------------------------------------------------------
// CSR build
// ---------------------------------------------------------------------------
__global__ void hist_kernel(const int* __restrict__ ei, int* __restrict__ counts) {
  int e = blockIdx.x * 256 + threadIdx.x;
  if (e < EE) atomicAdd(&counts[ei[EE + e]], 1);
}

__global__ __launch_bounds__(1024) void scan_kernel(const int* __restrict__ counts,
                                                    int* __restrict__ offsets,
                                                    int* __restrict__ cursor) {
  __shared__ int sums[1024];
  const int t = threadIdx.x;
  const int PER = 20;
  int base = t * PER;
  int loc[PER]; int s = 0;
  #pragma unroll
  for (int i = 0; i < PER; ++i) {
    int idx = base + i;
    int c = (idx < NN) ? counts[idx] : 0;
    loc[i] = s; s += c;
  }
  sums[t] = s;
  __syncthreads();
  for (int d = 1; d < 1024; d <<= 1) {
    int v = (t >= d) ? sums[t - d] : 0;
    __syncthreads();
    sums[t] += v;
    __syncthreads();
  }
  int pre = (t > 0) ? sums[t - 1] : 0;
  #pragma unroll
  for (int i = 0; i < PER; ++i) {
    int idx = base + i;
    if (idx < NN) { offsets[idx] = pre + loc[i]; cursor[idx] = pre + loc[i]; }
  }
  if (t == 0) offsets[NN] = sums[1023];
}

__global__ void scatter_kernel(const int* __restrict__ ei, int* __restrict__ cursor,
                               int* __restrict__ csr) {
  int e = blockIdx.x * 256 + threadIdx.x;
  if (e < EE) {
    int p = atomicAdd(&cursor[ei[EE + e]], 1);
    csr[p] = e;
  }
}

// ---------------------------------------------------------------------------
// Attention: global softmax over all E edge logits
// ---------------------------------------------------------------------------
__device__ inline void atomicMaxF(float* addr, float val) {
  if (val >= 0.f) atomicMax((int*)addr, __float_as_int(val));
  else            atomicMin((unsigned int*)addr, __float_as_uint(val));
}

// init both layers' {max, Z} slots
__global__ void init_scalars(float* scal) {
  if (threadIdx.x < NL) { scal[threadIdx.x * 2] = -INFINITY; scal[threadIdx.x * 2 + 1] = 0.f; }
}

__global__ __launch_bounds__(256) void attn_logits(
    const int* __restrict__ ei, const ushort_t* __restrict__ qkv,
    float* __restrict__ s_e, float* __restrict__ scal)
{
  const int tid = threadIdx.x;
  const int l = tid & 31;
  const int ngroups = ALB * 8;
  const int g = blockIdx.x * 8 + (tid >> 5);
  float mx = -FLT_MAX;
  for (int e = g; e < EE; e += 2 * ngroups) {
    const int e2 = e + ngroups;
    const bool has2 = (e2 < EE);
    int src1 = ei[e], dst1 = ei[EE + e];
    int src2 = has2 ? ei[e2] : src1;
    int dst2 = has2 ? ei[EE + e2] : dst1;
    uint2 qu1 = *(const uint2*)(qkv + (size_t)dst1 * NPROJ + l * 4);
    uint2 ku1 = *(const uint2*)(qkv + (size_t)src1 * NPROJ + DH + l * 4);
    uint2 qu2 = *(const uint2*)(qkv + (size_t)dst2 * NPROJ + l * 4);
    uint2 ku2 = *(const uint2*)(qkv + (size_t)src2 * NPROJ + DH + l * 4);
    float d1 = bflo(qu1.x) * bflo(ku1.x) + bfhi(qu1.x) * bfhi(ku1.x)
             + bflo(qu1.y) * bflo(ku1.y) + bfhi(qu1.y) * bfhi(ku1.y);
    float d2 = bflo(qu2.x) * bflo(ku2.x) + bfhi(qu2.x) * bfhi(ku2.x)
             + bflo(qu2.y) * bflo(ku2.y) + bfhi(qu2.y) * bfhi(ku2.y);
    #pragma unroll
    for (int m = 16; m >= 1; m >>= 1) {
      d1 += __shfl_xor(d1, m);
      d2 += __shfl_xor(d2, m);
    }
    if (l == 0) {
      s_e[e] = d1;
      if (has2) s_e[e2] = d2;
    }
    mx = fmaxf(mx, has2 ? fmaxf(d1, d2) : d1);
  }
  mx = fmaxf(mx, __shfl_xor(mx, 32));
  __shared__ float red[4];
  if ((tid & 63) == 0) red[tid >> 6] = mx;
  __syncthreads();
  if (tid == 0)
    atomicMaxF(scal, fmaxf(fmaxf(red[0], red[1]), fmaxf(red[2], red[3])));
}

__global__ __launch_bounds__(256) void exp_sum(
    float* __restrict__ s_e, const float* __restrict__ scal, float* __restrict__ Z)
{
  const int e = blockIdx.x * 256 + threadIdx.x;
  const float mx = scal[0];
  float v = __expf(s_e[e] - mx);
  s_e[e] = v;
  float t = v;
  #pragma unroll
  for (int m = 32; m >= 1; m >>= 1) t += __shfl_xor(t, m);
  __shared__ float red[4];
  if ((threadIdx.x & 63) == 0) red[threadIdx.x >> 6] = t;
  __syncthreads();
  if (threadIdx.x == 0) atomicAdd(Z, red[0] + red[1] + red[2] + red[3]);
}

// ---------------------------------------------------------------------------
// Fused per-dst aggregation + LayerNorm1:
//   h[i] = r[i] + sum_e p_e * v[src] * gate_e ; ss = LN(h) (f32 + bf16 out)
// One wave per node; wave owns the full 128-wide row -> LN is two shfl reduces.
// ---------------------------------------------------------------------------
__global__ __launch_bounds__(256) void aggregate_ln_kernel(
    const int* __restrict__ ei, const int* __restrict__ offsets,
    const int* __restrict__ csr, const float* __restrict__ s_e,
    const float* __restrict__ scal, const ushort_t* __restrict__ qkv,
    const float* __restrict__ ea,
    const float* __restrict__ g, const float* __restrict__ b,
    float* __restrict__ ss, ushort_t* __restrict__ ssbf)
{
  const int node = blockIdx.x * 4 + (threadIdx.x >> 6);
  const int lane = threadIdx.x & 63;
  if (node >= NN) return;
  const int off = offsets[node];
  const int deg = offsets[node + 1] - off;
  const float invZ = 1.f / scal[1];
  const ushort_t* bd = qkv + (size_t)node * NPROJ;
  unsigned hjp = *(const unsigned*)(bd + 640 + lane * 2);
  unsigned rp  = *(const unsigned*)(bd + 384 + lane * 2);
  const float hj0 = bflo(hjp), hj1 = bfhi(hjp);
  float a0 = bflo(rp), a1 = bfhi(rp);
  for (int b0 = 0; b0 < deg; b0 += 64) {
    int t = b0 + lane;
    int eL = (t < deg) ? csr[off + t] : 0;
    int sL = (t < deg) ? ei[eL] : 0;
    float pL = (t < deg) ? s_e[eL] * invZ : 0.f;
    int cnt = min(64, deg - b0);
    for (int u = 0; u < cnt; ++u) {
      int e = __shfl(eL, u);
      int src = __shfl(sL, u);
      float p = __shfl(pL, u);
      const ushort_t* bs = qkv + (size_t)src * NPROJ;
      unsigned vv = *(const unsigned*)(bs + 256 + lane * 2);
      unsigned hv = *(const unsigned*)(bs + 512 + lane * 2);
      float2 eav = *(const float2*)(ea + (size_t)e * DH + lane * 2);
      float g0 = 1.f / (1.f + __expf(-(eav.x + bflo(hv) + hj0)));
      float g1 = 1.f / (1.f + __expf(-(eav.y + bfhi(hv) + hj1)));
      a0 = fmaf(p * bflo(vv), g0, a0);
      a1 = fmaf(p * bfhi(vv), g1, a1);
    }
  }
  // fused LN over (a0, a1) x 64 lanes
  float s = a0 + a1;
  #pragma unroll
  for (int m = 32; m >= 1; m >>= 1) s += __shfl_xor(s, m);
  float mean = s * (1.f / 128.f);
  float dx = a0 - mean, dy = a1 - mean;
  float v = dx * dx + dy * dy;
  #pragma unroll
  for (int m = 32; m >= 1; m >>= 1) v += __shfl_xor(v, m);
  float rstd = rsqrtf(v * (1.f / 128.f) + 1e-5f);
  float2 gg = *(const float2*)(g + lane * 2);
  float2 bb = *(const float2*)(b + lane * 2);
  float o0 = dx * rstd * gg.x + bb.x;
  float o1 = dy * rstd * gg.y + bb.y;
  *(float2*)(ss + (size_t)node * DH + lane * 2) = make_float2(o0, o1);
  ushort_t* pp = ssbf + (size_t)node * DH + lane * 2;
  pp[0] = f2bf(o0); pp[1] = f2bf(o1);
}

// ---------------------------------------------------------------------------
// LayerNorm over rows of 128 (X+X2), writes bf16.
// ---------------------------------------------------------------------------
__global__ __launch_bounds__(256) void ln_kernel(
    const float* __restrict__ X, const float* __restrict__ X2,
    const float* __restrict__ g, const float* __restrict__ b,
    float* __restrict__ Yf, ushort_t* __restrict__ Yb)
{
  int row = blockIdx.x * 4 + (threadIdx.x >> 6);
  int lane = threadIdx.x & 63;
  if (row >= NN) return;
  float2 x = *(const float2*)(X + (size_t)row * DH + lane * 2);
  if (X2) {
    float2 y = *(const float2*)(X2 + (size_t)row * DH + lane * 2);
    x.x += y.x; x.y += y.y;
  }
  float s = x.x + x.y;
  #pragma unroll
  for (int m = 32; m >= 1; m >>= 1) s += __shfl_xor(s, m);
  float mean = s * (1.f / 128.f);
  float dx = x.x - mean, dy = x.y - mean;
  float v = dx * dx + dy * dy;
  #pragma unroll
  for (int m = 32; m >= 1; m >>= 1) v += __shfl_xor(v, m);
  float rstd = rsqrtf(v * (1.f / 128.f) + 1e-5f);
  float2 gg = *(const float2*)(g + lane * 2);
  float2 bb = *(const float2*)(b + lane * 2);
  float o0 = dx * rstd * gg.x + bb.x;
  float o1 = dy * rstd * gg.y + bb.y;
  if (Yf) *(float2*)(Yf + (size_t)row * DH + lane * 2) = make_float2(o0, o1);
  if (Yb) {
    ushort_t* p = Yb + (size_t)row * DH + lane * 2;
    p[0] = f2bf(o0); p[1] = f2bf(o1);
  }
}

// ---------------------------------------------------------------------------
extern "C" void kernel_launch(void* const* d_in, const int* in_sizes, int n_in,
                              void* d_out, int out_size, void* d_ws, size_t ws_size,
                              hipStream_t stream)
{
  const float* x_in  = (const float*)d_in[0];
  const int*   ei    = (const int*)d_in[1];
  const float* ea    = (const float*)d_in[2];
  const float* Wq    = (const float*)d_in[3];
  const float* bq    = (const float*)d_in[4];
  const float* Wk    = (const float*)d_in[5];
  const float* bk    = (const float*)d_in[6];
  const float* Wv    = (const float*)d_in[7];
  const float* bv    = (const float*)d_in[8];
  const float* Wr    = (const float*)d_in[9];
  const float* br    = (const float*)d_in[10];
  const float* Whi   = (const float*)d_in[11];
  const float* Whj   = (const float*)d_in[12];
  const float* W1    = (const float*)d_in[13];
  const float* b1    = (const float*)d_in[14];
  const float* W2    = (const float*)d_in[15];
  const float* b2    = (const float*)d_in[16];
  const float* g1    = (const float*)d_in[17];
  const float* be1   = (const float*)d_in[18];
  const float* g2    = (const float*)d_in[19];
  const float* be2   = (const float*)d_in[20];
  const float* linW  = (const float*)d_in[21];
  const float* linb  = (const float*)d_in[22];
  const float* lin2W = (const float*)d_in[23];
  const float* lin2b = (const float*)d_in[24];
  float* out = (float*)d_out;

  char* p = (char*)d_ws;
  auto alloc = [&](size_t bytes) -> void* {
    void* r = (void*)p; p += (bytes + 63) & ~((size_t)63); return r;
  };
  ushort_t* x_bf   = (ushort_t*)alloc((size_t)NN * KIN * 2);
  ushort_t* qkvp   = (ushort_t*)alloc((size_t)NN * NPROJ * 2);
  ushort_t* Wt6    = (ushort_t*)alloc((size_t)NPROJ * KIN * 2);
  ushort_t* W1t    = (ushort_t*)alloc((size_t)DFF * DH * 2);
  ushort_t* W2t    = (ushort_t*)alloc((size_t)DH * DFF * 2);
  ushort_t* Wc6    = (ushort_t*)alloc((size_t)NPROJ * DH * 2);  // folded layer-1 proj
  ushort_t* Wcf    = (ushort_t*)alloc((size_t)DH * DH * 2);     // folded final linear
  float*    bias768= (float*)alloc(NPROJ * 4);
  float*    bc768  = (float*)alloc(NPROJ * 4);
  float*    bcf    = (float*)alloc(DH * 4);
  float*    s_e    = (float*)alloc((size_t)EE * 4);
  float*    scal   = (float*)alloc(64);
  int*      counts = (int*)alloc((size_t)NN * 4);
  int*      offsets= (int*)alloc((size_t)(NN + 1) * 4);
  int*      cursor = (int*)alloc((size_t)NN * 4);
  int*      csr    = (int*)alloc((size_t)EE * 4);
  float*    ss     = (float*)alloc((size_t)NN * DH * 4);
  ushort_t* ssbf   = (ushort_t*)alloc((size_t)NN * DH * 2);
  ushort_t* ff1bf  = (ushort_t*)alloc((size_t)NN * DFF * 2);
  float*    ss2    = (float*)alloc((size_t)NN * DH * 4);
  ushort_t* h2bf   = (ushort_t*)alloc((size_t)NN * DH * 2);

  const dim3 blk(256);
  const int MB = (NN + 127) / 128;  // 157

  // --- setup: convert x, build CSR, fold linW, init softmax scalars ---
  convert_x_kernel<<<dim3((NN * (KIN / 8) + 255) / 256), blk, 0, stream>>>(x_in, x_bf);
  hipMemsetAsync(counts, 0, (size_t)NN * 4, stream);
  hist_kernel<<<dim3(EE / 256), blk, 0, stream>>>(ei, counts);
  scan_kernel<<<dim3(1), dim3(1024), 0, stream>>>(counts, offsets, cursor);
  scatter_kernel<<<dim3(EE / 256), blk, 0, stream>>>(ei, cursor, csr);

  const size_t wo1 = (size_t)DIN * DH;
  combine6_kernel<<<dim3(NPROJ / 2), blk, 0, stream>>>(
      Wq + wo1, Wk + wo1, Wv + wo1, Wr + wo1, Whi + wo1, Whj + wo1,
      bq + DH, bk + DH, bv + DH, br + DH, linW, linb, Wc6, bc768);
  combine_fin_kernel<<<dim3(DH / 2), blk, 0, stream>>>(
      lin2W, lin2b, linW, linb, Wcf, bcf);
  init_scalars<<<1, 64, 0, stream>>>(scal);

  for (int l = 0; l < NL; ++l) {
    pack_bt_kernel<<<dim3(1, DFF), blk, 0, stream>>>(W1 + (size_t)l * DH * DFF, W1t, DFF, DH, DH);
    pack_bt_kernel<<<dim3(2, DH), blk, 0, stream>>>(W2 + (size_t)l * DFF * DH, W2t, DH, DFF, DFF);

    if (l == 0) {
      pack6t_kernel<<<dim3(KIN / 32, NPROJ / 32), blk, 0, stream>>>(
          Wq, Wk, Wv, Wr, Whi, Whj, Wt6);
      pack_bias_kernel<<<dim3(3), blk, 0, stream>>>(bq, bk, bv, br, bias768);
      gemm_bf16<<<dim3(MB, 6), blk, 0, stream>>>(
          x_bf, KIN, Wt6, KIN, bias768, qkvp, NPROJ, NN, NPROJ, KIN, 0, 1);
    } else {
      gemm_bf16<<<dim3(MB, 6), blk, 0, stream>>>(
          h2bf, DH, Wc6, DH, bc768, qkvp, NPROJ, NN, NPROJ, DH, 0, 1);
    }

    // global-softmax attention + fused aggregation/LN1
    attn_logits<<<dim3(ALB), blk, 0, stream>>>(ei, qkvp, s_e, scal + l * 2);
    exp_sum<<<dim3(EE / 256), blk, 0, stream>>>(s_e, scal + l * 2, scal + l * 2 + 1);
    aggregate_ln_kernel<<<dim3(NN / 4), blk, 0, stream>>>(
        ei, offsets, csr, s_e, scal + l * 2, qkvp, ea,
        g1 + (size_t)l * DH, be1 + (size_t)l * DH, ss, ssbf);

    // FFMLP
    gemm_bf16<<<dim3(MB, 4), blk, 0, stream>>>(
        ssbf, DH, W1t, DH, b1 + (size_t)l * DFF, ff1bf, DFF, NN, DFF, DH, 1, 1);
    gemm_bf16<<<dim3(MB, 1), blk, 0, stream>>>(
        ff1bf, DFF, W2t, DFF, b2 + (size_t)l * DH, ss2, DH, NN, DH, DFF, 0, 0);
    ln_kernel<<<dim3(NN / 4), blk, 0, stream>>>(ss, ss2, g2 + (size_t)l * DH, be2 + (size_t)l * DH, nullptr, h2bf);
  }

  // final: folded (linW @ lin2W) 128 -> 128 + leaky_relu, fp32 out
  gemm_bf16<<<dim3(MB, 1), blk, 0, stream>>>(
      h2bf, DH, Wcf, DH, bcf, out, DH, NN, DH, DH, 2, 0);
}

// Round 5
// 1435.654 us; speedup vs baseline: 1.1212x; 1.1030x over previous
//
#include <hip/hip_runtime.h>
#include <cfloat>
#include <cmath>

#define NN 20000
#define EE 640000
#define DIN 1546
#define KIN 1568   // DIN padded to multiple of 32
#define DH 128
#define DFF 512
#define NL 2
#define NPROJ 768   // q|k|v|r|hi|hj packed columns
#define NB (NN / 4) // node-parallel blocks (4 waves/block, 1 node/wave)

typedef unsigned short ushort_t;
typedef __attribute__((ext_vector_type(8))) short short8;
typedef __attribute__((ext_vector_type(8))) unsigned short ushort8;
typedef __attribute__((ext_vector_type(4))) float floatx4;

__device__ inline ushort_t f2bf(float f) {
  unsigned u = __float_as_uint(f);
  unsigned r = (u + 0x7FFF + ((u >> 16) & 1)) >> 16;
  return (ushort_t)r;
}
__device__ inline float bflo(unsigned u) { return __uint_as_float(u << 16); }
__device__ inline float bfhi(unsigned u) { return __uint_as_float(u & 0xFFFF0000u); }

// ---------------------------------------------------------------------------
// bf16 MFMA GEMM: C[M x N] = act(A[M x K] @ Bt[N x K]^T + bias)
// Reg-staged (harness-proven structure). Bt has exactly gridDim.y*128 rows.
// act: 0 none, 1 relu, 2 leaky(0.01).  out_bf16: 1 -> ushort C, 0 -> float C.
// ---------------------------------------------------------------------------
__global__ __launch_bounds__(256) void gemm_bf16(
    const ushort_t* __restrict__ A, int lda,
    const ushort_t* __restrict__ Bt, int ldb,
    const float* __restrict__ bias, void* __restrict__ Cv, int ldc,
    int M, int Nstore, int K, int act, int out_bf16)
{
  __shared__ ushort_t As[4 * 1032];
  __shared__ ushort_t Bs[4 * 1032];
  const int tid = threadIdx.x;
  const int wave = tid >> 6, lane = tid & 63;
  const int bm = blockIdx.x * 128, bn = blockIdx.y * 128;
  const int wm = (wave >> 1) * 64, wn = (wave & 1) * 64;
  const int frow = lane & 15, kq = lane >> 4;

  floatx4 acc[4][4];
  #pragma unroll
  for (int i = 0; i < 4; ++i)
    #pragma unroll
    for (int j = 0; j < 4; ++j) acc[i][j] = (floatx4){0.f, 0.f, 0.f, 0.f};

  const int srow = tid >> 2, skc = tid & 3;
  const int ar0 = min(bm + srow, M - 1);
  const int ar1 = min(bm + srow + 64, M - 1);
  const ushort_t* Ap0 = A + (size_t)ar0 * lda + skc * 8;
  const ushort_t* Ap1 = A + (size_t)ar1 * lda + skc * 8;
  const ushort_t* Bp0 = Bt + (size_t)(bn + srow) * ldb + skc * 8;
  const ushort_t* Bp1 = Bt + (size_t)(bn + srow + 64) * ldb + skc * 8;
  ushort_t* Aw0 = As + skc * 1032 + srow * 8;
  ushort_t* Aw1 = As + skc * 1032 + (srow + 64) * 8;
  ushort_t* Bw0 = Bs + skc * 1032 + srow * 8;
  ushort_t* Bw1 = Bs + skc * 1032 + (srow + 64) * 8;

  for (int k0 = 0; k0 < K; k0 += 32) {
    ushort8 a0 = *(const ushort8*)Ap0; Ap0 += 32;
    ushort8 a1 = *(const ushort8*)Ap1; Ap1 += 32;
    ushort8 b0 = *(const ushort8*)Bp0; Bp0 += 32;
    ushort8 b1 = *(const ushort8*)Bp1; Bp1 += 32;
    __syncthreads();
    *(ushort8*)Aw0 = a0; *(ushort8*)Aw1 = a1;
    *(ushort8*)Bw0 = b0; *(ushort8*)Bw1 = b1;
    __syncthreads();
    short8 af[4], bfv[4];
    #pragma unroll
    for (int i = 0; i < 4; ++i)
      af[i] = *(const short8*)(As + kq * 1032 + (wm + i * 16 + frow) * 8);
    #pragma unroll
    for (int j = 0; j < 4; ++j)
      bfv[j] = *(const short8*)(Bs + kq * 1032 + (wn + j * 16 + frow) * 8);
    #pragma unroll
    for (int i = 0; i < 4; ++i)
      #pragma unroll
      for (int j = 0; j < 4; ++j)
        acc[i][j] = __builtin_amdgcn_mfma_f32_16x16x32_bf16(af[i], bfv[j], acc[i][j], 0, 0, 0);
  }

  const int rq = (lane >> 4) * 4;
  #pragma unroll
  for (int j = 0; j < 4; ++j) {
    int col = bn + wn + j * 16 + frow;
    if (col >= Nstore) continue;
    float bb = bias ? bias[col] : 0.f;
    #pragma unroll
    for (int i = 0; i < 4; ++i) {
      #pragma unroll
      for (int r = 0; r < 4; ++r) {
        int row = bm + wm + i * 16 + rq + r;
        if (row >= M) continue;
        float v = acc[i][j][r] + bb;
        if (act == 1) v = fmaxf(v, 0.f);
        else if (act == 2) v = v > 0.f ? v : 0.01f * v;
        if (out_bf16) ((ushort_t*)Cv)[(size_t)row * ldc + col] = f2bf(v);
        else          ((float*)Cv)[(size_t)row * ldc + col] = v;
      }
    }
  }
}

// ---------------------------------------------------------------------------
// ff2 GEMM (K=DFF, 128 output cols) with fused LN2: h2 = LN(ss + (A@W2t^T + b2))
// Block owns full 128-wide rows -> LN via LDS stage + per-row wave reduce.
// ---------------------------------------------------------------------------
__global__ __launch_bounds__(256) void gemm_ff2_ln(
    const ushort_t* __restrict__ A,          // ff1bf [M][DFF]
    const ushort_t* __restrict__ Bt,         // W2t [DH][DFF]
    const float* __restrict__ bias,          // b2 [DH]
    const float* __restrict__ ss,            // [M][DH] residual input
    const float* __restrict__ g, const float* __restrict__ b,
    ushort_t* __restrict__ Yb, int M)        // h2bf
{
  __shared__ ushort_t As[4 * 1032];
  __shared__ ushort_t Bs[4 * 1032];
  __shared__ float vrow[128][130];
  const int tid = threadIdx.x;
  const int wave = tid >> 6, lane = tid & 63;
  const int bm = blockIdx.x * 128;
  const int wm = (wave >> 1) * 64, wn = (wave & 1) * 64;
  const int frow = lane & 15, kq = lane >> 4;

  floatx4 acc[4][4];
  #pragma unroll
  for (int i = 0; i < 4; ++i)
    #pragma unroll
    for (int j = 0; j < 4; ++j) acc[i][j] = (floatx4){0.f, 0.f, 0.f, 0.f};

  const int srow = tid >> 2, skc = tid & 3;
  const ushort_t* Ap0 = A + (size_t)min(bm + srow, M - 1) * DFF + skc * 8;
  const ushort_t* Ap1 = A + (size_t)min(bm + srow + 64, M - 1) * DFF + skc * 8;
  const ushort_t* Bp0 = Bt + (size_t)srow * DFF + skc * 8;
  const ushort_t* Bp1 = Bt + (size_t)(srow + 64) * DFF + skc * 8;
  ushort_t* Aw0 = As + skc * 1032 + srow * 8;
  ushort_t* Aw1 = As + skc * 1032 + (srow + 64) * 8;
  ushort_t* Bw0 = Bs + skc * 1032 + srow * 8;
  ushort_t* Bw1 = Bs + skc * 1032 + (srow + 64) * 8;

  for (int k0 = 0; k0 < DFF; k0 += 32) {
    ushort8 a0 = *(const ushort8*)Ap0; Ap0 += 32;
    ushort8 a1 = *(const ushort8*)Ap1; Ap1 += 32;
    ushort8 b0 = *(const ushort8*)Bp0; Bp0 += 32;
    ushort8 b1 = *(const ushort8*)Bp1; Bp1 += 32;
    __syncthreads();
    *(ushort8*)Aw0 = a0; *(ushort8*)Aw1 = a1;
    *(ushort8*)Bw0 = b0; *(ushort8*)Bw1 = b1;
    __syncthreads();
    short8 af[4], bfv[4];
    #pragma unroll
    for (int i = 0; i < 4; ++i)
      af[i] = *(const short8*)(As + kq * 1032 + (wm + i * 16 + frow) * 8);
    #pragma unroll
    for (int j = 0; j < 4; ++j)
      bfv[j] = *(const short8*)(Bs + kq * 1032 + (wn + j * 16 + frow) * 8);
    #pragma unroll
    for (int i = 0; i < 4; ++i)
      #pragma unroll
      for (int j = 0; j < 4; ++j)
        acc[i][j] = __builtin_amdgcn_mfma_f32_16x16x32_bf16(af[i], bfv[j], acc[i][j], 0, 0, 0);
  }

  // stage v = acc + b2 + ss into LDS (full 128x128 per block)
  const int rq = (lane >> 4) * 4;
  #pragma unroll
  for (int j = 0; j < 4; ++j) {
    int col = wn + j * 16 + frow;
    float bb = bias[col];
    #pragma unroll
    for (int i = 0; i < 4; ++i) {
      #pragma unroll
      for (int r = 0; r < 4; ++r) {
        int row = wm + i * 16 + rq + r;
        int grow = bm + row;
        float v = acc[i][j][r] + bb;
        if (grow < M) v += ss[(size_t)grow * DH + col];
        vrow[row][col] = v;
      }
    }
  }
  __syncthreads();

  // LN: wave handles 32 rows; lane owns 2 cols
  float2 gg = *(const float2*)(g + lane * 2);
  float2 bbv = *(const float2*)(b + lane * 2);
  for (int rr = 0; rr < 32; ++rr) {
    int row = wave * 32 + rr;
    int grow = bm + row;
    if (grow >= M) break;
    float x0 = vrow[row][lane * 2], x1 = vrow[row][lane * 2 + 1];
    float s = x0 + x1;
    #pragma unroll
    for (int m = 32; m >= 1; m >>= 1) s += __shfl_xor(s, m);
    float mean = s * (1.f / 128.f);
    float dx = x0 - mean, dy = x1 - mean;
    float v = dx * dx + dy * dy;
    #pragma unroll
    for (int m = 32; m >= 1; m >>= 1) v += __shfl_xor(v, m);
    float rstd = rsqrtf(v * (1.f / 128.f) + 1e-5f);
    float o0 = dx * rstd * gg.x + bbv.x;
    float o1 = dy * rstd * gg.y + bbv.y;
    ushort_t* pp = Yb + (size_t)grow * DH + lane * 2;
    pp[0] = f2bf(o0); pp[1] = f2bf(o1);
  }
}

// ---------------------------------------------------------------------------
// Pack / convert kernels
// ---------------------------------------------------------------------------
__global__ __launch_bounds__(256) void convert_x_kernel(
    const float* __restrict__ x, ushort_t* __restrict__ xb)
{
  const unsigned CPR = KIN / 8;  // 196 chunks per row
  unsigned gid = blockIdx.x * 256 + threadIdx.x;
  if (gid >= (unsigned)NN * CPR) return;
  unsigned row = gid / CPR;
  unsigned c8 = (gid - row * CPR) * 8;
  const float* xr = x + (size_t)row * DIN;
  ushort8 o;
  #pragma unroll
  for (int j = 0; j < 8; ++j)
    o[j] = (c8 + j < DIN) ? f2bf(xr[c8 + j]) : (ushort_t)0;
  *(ushort8*)(xb + (size_t)row * KIN + c8) = o;
}

// tiled-transpose pack of the 6 layer-0 projection weights
__global__ __launch_bounds__(256) void pack6t_kernel(
    const float* __restrict__ Wq, const float* __restrict__ Wk,
    const float* __restrict__ Wv, const float* __restrict__ Wr,
    const float* __restrict__ Whi, const float* __restrict__ Whj,
    ushort_t* __restrict__ Wt6)
{
  __shared__ float tile[32][33];
  const int k0 = blockIdx.x * 32;   // 49 -> 1568
  const int n0 = blockIdx.y * 32;   // 24 -> 768
  const float* Ws[6] = {Wq, Wk, Wv, Wr, Whi, Whj};
  const float* W = Ws[n0 >> 7];
  const int c0 = n0 & 127;
  const int tc = threadIdx.x & 31, tr = threadIdx.x >> 5;
  #pragma unroll
  for (int r = tr; r < 32; r += 8) {
    int k = k0 + r;
    tile[r][tc] = (k < DIN) ? W[(size_t)k * DH + c0 + tc] : 0.f;
  }
  __syncthreads();
  #pragma unroll
  for (int n = tr; n < 32; n += 8)
    Wt6[(size_t)(n0 + n) * KIN + k0 + tc] = f2bf(tile[tc][n]);
}

// one kernel packs W1t/W2t for BOTH layers + bias768 (layer 0).
// y: [0,512) W1t0 | [512,1024) W1t1 | [1024,1152) W2t0 | [1152,1280) W2t1 | [1280,1283) bias
__global__ void pack_small_kernel(
    const float* __restrict__ W1, const float* __restrict__ W2,
    const float* __restrict__ bq, const float* __restrict__ bk,
    const float* __restrict__ bv, const float* __restrict__ br,
    ushort_t* __restrict__ W1t0, ushort_t* __restrict__ W1t1,
    ushort_t* __restrict__ W2t0, ushort_t* __restrict__ W2t1,
    float* __restrict__ bias768)
{
  const int y = blockIdx.y;
  const int tid = threadIdx.x;
  if (y < 1024) {                     // W1t[l][n][k] = W1[l][k][n], k<DH
    int l = y >> 9, n = y & 511;
    const float* src = W1 + (size_t)l * DH * DFF;
    ushort_t* dst = l ? W1t1 : W1t0;
    if (tid < DH) dst[(size_t)n * DH + tid] = f2bf(src[(size_t)tid * DFF + n]);
  } else if (y < 1280) {              // W2t[l][n][k] = W2[l][k][n], k<DFF
    int l = (y - 1024) >> 7, n = (y - 1024) & 127;
    const float* src = W2 + (size_t)l * DFF * DH;
    ushort_t* dst = l ? W2t1 : W2t0;
    for (int k = tid; k < DFF; k += 256)
      dst[(size_t)n * DFF + k] = f2bf(src[(size_t)k * DH + n]);
  } else {
    int n = (y - 1280) * 256 + tid;
    if (n < NPROJ) {
      int which = n >> 7, c = n & 127;
      float v = 0.f;
      if (which == 0) v = bq[c]; else if (which == 1) v = bk[c];
      else if (which == 2) v = bv[c]; else if (which == 3) v = br[c];
      bias768[n] = v;
    }
  }
}

// ---------------------------------------------------------------------------
// Weight folding (combine6 + combine_fin merged):
//   x @ W + b == h @ (linW @ W) + (linb @ W + b), exact f32, one bf16 round.
// blocks [0,384): 6-proj fold -> Wc6/bc768; [384,448): lin2 fold -> Wcf/bcf.
// ---------------------------------------------------------------------------
__global__ __launch_bounds__(256) void combine_all_kernel(
    const float* __restrict__ Wq, const float* __restrict__ Wk,
    const float* __restrict__ Wv, const float* __restrict__ Wr,
    const float* __restrict__ Whi, const float* __restrict__ Whj,
    const float* __restrict__ bq, const float* __restrict__ bk,
    const float* __restrict__ bv, const float* __restrict__ br,
    const float* __restrict__ lin2W, const float* __restrict__ lin2b,
    const float* __restrict__ linW, const float* __restrict__ linb,
    ushort_t* __restrict__ Pc, float* __restrict__ bc,
    ushort_t* __restrict__ Pf, float* __restrict__ bf_out)
{
  const int j = threadIdx.x >> 7;
  const int k = threadIdx.x & 127;
  const bool six = blockIdx.x < (NPROJ / 2);
  const int n = six ? blockIdx.x * 2 + j : (blockIdx.x - NPROJ / 2) * 2 + j;
  const float* Ws[6] = {Wq, Wk, Wv, Wr, Whi, Whj};
  const float* W = six ? Ws[n >> 7] : lin2W;
  const int col = six ? (n & 127) : n;
  __shared__ float wcol[2][DIN];
  for (int d = k; d < DIN; d += 128)
    wcol[j][d] = W[(size_t)d * DH + col];
  __syncthreads();
  const float* lr = linW + (size_t)k * DIN;
  float acc = 0.f;
  #pragma unroll 4
  for (int d = 0; d < DIN; d += 2) {
    float2 lv = *(const float2*)(lr + d);
    acc = fmaf(wcol[j][d], lv.x, acc);
    acc = fmaf(wcol[j][d + 1], lv.y, acc);
  }
  if (six) Pc[(size_t)n * DH + k] = f2bf(acc);
  else     Pf[(size_t)n * DH + k] = f2bf(acc);
  float bs = 0.f;
  for (int d = k; d < DIN; d += 128) bs += linb[d] * wcol[j][d];
  #pragma unroll
  for (int m = 32; m >= 1; m >>= 1) bs += __shfl_xor(bs, m);
  __shared__ float red[4];
  if ((threadIdx.x & 63) == 0) red[threadIdx.x >> 6] = bs;
  __syncthreads();
  if (k == 0) {
    float tot = red[j * 2] + red[j * 2 + 1];
    if (six) {
      int which = n >> 7, c = n & 127;
      float b0 = 0.f;
      if (which == 0) b0 = bq[c]; else if (which == 1) b0 = bk[c];
      else if (which == 2) b0 = bv[c]; else if (which == 3) b0 = br[c];
      bc[n] = b0 + tot;
    } else {
      bf_out[n] = lin2b[n] + tot;
    }
  }
}

// ---------------------------------------------------------------------------
// CSR build (csrc[pos]=src node, cea[pos]=edge id)
// ---------------------------------------------------------------------------
__global__ void hist_kernel(const int* __restrict__ ei, int* __restrict__ counts) {
  int e = blockIdx.x * 256 + threadIdx.x;
  if (e < EE) atomicAdd(&counts[ei[EE + e]], 1);
}

__global__ __launch_bounds__(1024) void scan_kernel(const int* __restrict__ counts,
                                                    int* __restrict__ offsets,
                                                    int* __restrict__ cursor) {
  __shared__ int sums[1024];
  const int t = threadIdx.x;
  const int PER = 20;
  int base = t * PER;
  int loc[PER]; int s = 0;
  #pragma unroll
  for (int i = 0; i < PER; ++i) {
    int idx = base + i;
    int c = (idx < NN) ? counts[idx] : 0;
    loc[i] = s; s += c;
  }
  sums[t] = s;
  __syncthreads();
  for (int d = 1; d < 1024; d <<= 1) {
    int v = (t >= d) ? sums[t - d] : 0;
    __syncthreads();
    sums[t] += v;
    __syncthreads();
  }
  int pre = (t > 0) ? sums[t - 1] : 0;
  #pragma unroll
  for (int i = 0; i < PER; ++i) {
    int idx = base + i;
    if (idx < NN) { offsets[idx] = pre + loc[i]; cursor[idx] = pre + loc[i]; }
  }
  if (t == 0) offsets[NN] = sums[1023];
}

__global__ void scatter_kernel(const int* __restrict__ ei, int* __restrict__ cursor,
                               int* __restrict__ csrc, int* __restrict__ cea) {
  int e = blockIdx.x * 256 + threadIdx.x;
  if (e < EE) {
    int src = ei[e];
    int p = atomicAdd(&cursor[ei[EE + e]], 1);
    csrc[p] = src;
    cea[p] = e;
  }
}

// ---------------------------------------------------------------------------
// CSR-ordered attention logits + per-block online softmax stats.
// One wave per node; q register-resident; two 32-lane halves, one edge each.
// Writes raw s_csr[pos] and per-block (m_b, Z_b).
// ---------------------------------------------------------------------------
__global__ __launch_bounds__(256) void attn_logits_csr(
    const int* __restrict__ offsets, const int* __restrict__ csrc,
    const ushort_t* __restrict__ qkv, float* __restrict__ s_csr,
    float* __restrict__ mb, float* __restrict__ zb)
{
  const int node = blockIdx.x * 4 + (threadIdx.x >> 6);
  const int lane = threadIdx.x & 63;
  const int sub = lane & 31, hh = lane >> 5;
  float m = -FLT_MAX, z = 0.f;
  if (node < NN) {
    const int off = offsets[node];
    const int deg = offsets[node + 1] - off;
    uint2 qu = *(const uint2*)(qkv + (size_t)node * NPROJ + sub * 4);
    float q0 = bflo(qu.x), q1 = bfhi(qu.x), q2 = bflo(qu.y), q3 = bfhi(qu.y);
    for (int t = hh; t < deg; t += 2) {
      int pos = off + t;
      int src = csrc[pos];
      uint2 ku = *(const uint2*)(qkv + (size_t)src * NPROJ + DH + sub * 4);
      float d = q0 * bflo(ku.x) + q1 * bfhi(ku.x) + q2 * bflo(ku.y) + q3 * bfhi(ku.y);
      #pragma unroll
      for (int mm = 16; mm >= 1; mm >>= 1) d += __shfl_xor(d, mm);
      if (sub == 0) s_csr[pos] = d;
      if (d <= m) z += __expf(d - m);
      else { z = z * __expf(m - d) + 1.f; m = d; }
    }
  }
  // merge the two halves (uniform per half)
  {
    float mo = __shfl_xor(m, 32), zo = __shfl_xor(z, 32);
    float mn = fmaxf(m, mo);
    z = z * __expf(m - mn) + zo * __expf(mo - mn);
    m = mn;
  }
  __shared__ float ms[4], zs[4];
  if (lane == 0) { ms[threadIdx.x >> 6] = m; zs[threadIdx.x >> 6] = z; }
  __syncthreads();
  if (threadIdx.x == 0) {
    float M4 = fmaxf(fmaxf(ms[0], ms[1]), fmaxf(ms[2], ms[3]));
    float Z4 = zs[0] * __expf(ms[0] - M4) + zs[1] * __expf(ms[1] - M4)
             + zs[2] * __expf(ms[2] - M4) + zs[3] * __expf(ms[3] - M4);
    mb[blockIdx.x] = M4; zb[blockIdx.x] = Z4;
  }
}

// merge NB (m,Z) pairs -> scal[0]=M, scal[1]=Z  (single block)
__global__ __launch_bounds__(1024) void smreduce_kernel(
    const float* __restrict__ mb, const float* __restrict__ zb,
    float* __restrict__ scal)
{
  const int t = threadIdx.x;
  float m = -FLT_MAX, z = 0.f;
  for (int i = t; i < NB; i += 1024) {
    float mi = mb[i], zi = zb[i];
    float mn = fmaxf(m, mi);
    z = z * __expf(m - mn) + zi * __expf(mi - mn);
    m = mn;
  }
  #pragma unroll
  for (int s = 32; s >= 1; s >>= 1) {
    float mo = __shfl_xor(m, s), zo = __shfl_xor(z, s);
    float mn = fmaxf(m, mo);
    z = z * __expf(m - mn) + zo * __expf(mo - mn);
    m = mn;
  }
  __shared__ float ms[16], zs[16];
  if ((t & 63) == 0) { ms[t >> 6] = m; zs[t >> 6] = z; }
  __syncthreads();
  if (t == 0) {
    float M = ms[0], Z = zs[0];
    for (int i = 1; i < 16; ++i) {
      float mn = fmaxf(M, ms[i]);
      Z = Z * __expf(M - mn) + zs[i] * __expf(ms[i] - mn);
      M = mn;
    }
    scal[0] = M; scal[1] = Z;
  }
}

// ---------------------------------------------------------------------------
// Fused per-dst aggregation + LN1. p = exp(s - M)/Z computed inline.
// ---------------------------------------------------------------------------
__global__ __launch_bounds__(256) void aggregate_ln_kernel(
    const int* __restrict__ offsets, const int* __restrict__ csrc,
    const int* __restrict__ cea, const float* __restrict__ s_csr,
    const float* __restrict__ scal, const ushort_t* __restrict__ qkv,
    const float* __restrict__ ea,
    const float* __restrict__ g, const float* __restrict__ b,
    float* __restrict__ ss, ushort_t* __restrict__ ssbf)
{
  const int node = blockIdx.x * 4 + (threadIdx.x >> 6);
  const int lane = threadIdx.x & 63;
  if (node >= NN) return;
  const int off = offsets[node];
  const int deg = offsets[node + 1] - off;
  const float M = scal[0];
  const float invZ = 1.f / scal[1];
  const ushort_t* bd = qkv + (size_t)node * NPROJ;
  unsigned hjp = *(const unsigned*)(bd + 640 + lane * 2);
  unsigned rp  = *(const unsigned*)(bd + 384 + lane * 2);
  const float hj0 = bflo(hjp), hj1 = bfhi(hjp);
  float a0 = bflo(rp), a1 = bfhi(rp);
  for (int b0 = 0; b0 < deg; b0 += 64) {
    int t = b0 + lane;
    bool valid = t < deg;
    int pos = off + (valid ? t : 0);
    int sL = valid ? csrc[pos] : 0;
    int eL = valid ? cea[pos] : 0;
    float pL = valid ? __expf(s_csr[pos] - M) * invZ : 0.f;
    int cnt = min(64, deg - b0);
    for (int u = 0; u < cnt; ++u) {
      int e = __shfl(eL, u);
      int src = __shfl(sL, u);
      float p = __shfl(pL, u);
      const ushort_t* bs = qkv + (size_t)src * NPROJ;
      unsigned vv = *(const unsigned*)(bs + 256 + lane * 2);
      unsigned hv = *(const unsigned*)(bs + 512 + lane * 2);
      float2 eav = *(const float2*)(ea + (size_t)e * DH + lane * 2);
      float g0 = 1.f / (1.f + __expf(-(eav.x + bflo(hv) + hj0)));
      float g1 = 1.f / (1.f + __expf(-(eav.y + bfhi(hv) + hj1)));
      a0 = fmaf(p * bflo(vv), g0, a0);
      a1 = fmaf(p * bfhi(vv), g1, a1);
    }
  }
  // fused LN1
  float s = a0 + a1;
  #pragma unroll
  for (int m = 32; m >= 1; m >>= 1) s += __shfl_xor(s, m);
  float mean = s * (1.f / 128.f);
  float dx = a0 - mean, dy = a1 - mean;
  float v = dx * dx + dy * dy;
  #pragma unroll
  for (int m = 32; m >= 1; m >>= 1) v += __shfl_xor(v, m);
  float rstd = rsqrtf(v * (1.f / 128.f) + 1e-5f);
  float2 gg = *(const float2*)(g + lane * 2);
  float2 bb = *(const float2*)(b + lane * 2);
  float o0 = dx * rstd * gg.x + bb.x;
  float o1 = dy * rstd * gg.y + bb.y;
  *(float2*)(ss + (size_t)node * DH + lane * 2) = make_float2(o0, o1);
  ushort_t* pp = ssbf + (size_t)node * DH + lane * 2;
  pp[0] = f2bf(o0); pp[1] = f2bf(o1);
}

// ---------------------------------------------------------------------------
extern "C" void kernel_launch(void* const* d_in, const int* in_sizes, int n_in,
                              void* d_out, int out_size, void* d_ws, size_t ws_size,
                              hipStream_t stream)
{
  const float* x_in  = (const float*)d_in[0];
  const int*   ei    = (const int*)d_in[1];
  const float* ea    = (const float*)d_in[2];
  const float* Wq    = (const float*)d_in[3];
  const float* bq    = (const float*)d_in[4];
  const float* Wk    = (const float*)d_in[5];
  const float* bk    = (const float*)d_in[6];
  const float* Wv    = (const float*)d_in[7];
  const float* bv    = (const float*)d_in[8];
  const float* Wr    = (const float*)d_in[9];
  const float* br    = (const float*)d_in[10];
  const float* Whi   = (const float*)d_in[11];
  const float* Whj   = (const float*)d_in[12];
  const float* W1    = (const float*)d_in[13];
  const float* b1    = (const float*)d_in[14];
  const float* W2    = (const float*)d_in[15];
  const float* b2    = (const float*)d_in[16];
  const float* g1    = (const float*)d_in[17];
  const float* be1   = (const float*)d_in[18];
  const float* g2    = (const float*)d_in[19];
  const float* be2   = (const float*)d_in[20];
  const float* linW  = (const float*)d_in[21];
  const float* linb  = (const float*)d_in[22];
  const float* lin2W = (const float*)d_in[23];
  const float* lin2b = (const float*)d_in[24];
  float* out = (float*)d_out;

  char* p = (char*)d_ws;
  auto alloc = [&](size_t bytes) -> void* {
    void* r = (void*)p; p += (bytes + 63) & ~((size_t)63); return r;
  };
  ushort_t* x_bf   = (ushort_t*)alloc((size_t)NN * KIN * 2);
  ushort_t* qkvp   = (ushort_t*)alloc((size_t)NN * NPROJ * 2);
  ushort_t* Wt6    = (ushort_t*)alloc((size_t)NPROJ * KIN * 2);
  ushort_t* W1t0   = (ushort_t*)alloc((size_t)DFF * DH * 2);
  ushort_t* W1t1   = (ushort_t*)alloc((size_t)DFF * DH * 2);
  ushort_t* W2t0   = (ushort_t*)alloc((size_t)DH * DFF * 2);
  ushort_t* W2t1   = (ushort_t*)alloc((size_t)DH * DFF * 2);
  ushort_t* Wc6    = (ushort_t*)alloc((size_t)NPROJ * DH * 2);  // folded layer-1 proj
  ushort_t* Wcf    = (ushort_t*)alloc((size_t)DH * DH * 2);     // folded final linear
  float*    bias768= (float*)alloc(NPROJ * 4);
  float*    bc768  = (float*)alloc(NPROJ * 4);
  float*    bcf    = (float*)alloc(DH * 4);
  float*    s_csr  = (float*)alloc((size_t)EE * 4);
  float*    scal   = (float*)alloc(64);
  int*      counts = (int*)alloc((size_t)NN * 4);
  int*      offsets= (int*)alloc((size_t)(NN + 1) * 4);
  int*      cursor = (int*)alloc((size_t)NN * 4);
  int*      csrc   = (int*)alloc((size_t)EE * 4);
  int*      cea    = (int*)alloc((size_t)EE * 4);
  float*    mb     = (float*)alloc((size_t)NB * 4);
  float*    zb     = (float*)alloc((size_t)NB * 4);
  float*    ss     = (float*)alloc((size_t)NN * DH * 4);
  ushort_t* ssbf   = (ushort_t*)alloc((size_t)NN * DH * 2);
  ushort_t* ff1bf  = (ushort_t*)alloc((size_t)NN * DFF * 2);
  ushort_t* h2bf   = (ushort_t*)alloc((size_t)NN * DH * 2);

  const dim3 blk(256);
  const int MB = (NN + 127) / 128;  // 157

  // --- setup ---
  convert_x_kernel<<<dim3((NN * (KIN / 8) + 255) / 256), blk, 0, stream>>>(x_in, x_bf);
  hipMemsetAsync(counts, 0, (size_t)NN * 4, stream);
  hist_kernel<<<dim3(EE / 256), blk, 0, stream>>>(ei, counts);
  scan_kernel<<<dim3(1), dim3(1024), 0, stream>>>(counts, offsets, cursor);
  scatter_kernel<<<dim3(EE / 256), blk, 0, stream>>>(ei, cursor, csrc, cea);
  pack6t_kernel<<<dim3(KIN / 32, NPROJ / 32), blk, 0, stream>>>(
      Wq, Wk, Wv, Wr, Whi, Whj, Wt6);
  pack_small_kernel<<<dim3(1, 1283), blk, 0, stream>>>(
      W1, W2, bq, bk, bv, br, W1t0, W1t1, W2t0, W2t1, bias768);
  const size_t wo1 = (size_t)DIN * DH;
  combine_all_kernel<<<dim3(NPROJ / 2 + DH / 2), blk, 0, stream>>>(
      Wq + wo1, Wk + wo1, Wv + wo1, Wr + wo1, Whi + wo1, Whj + wo1,
      bq + DH, bk + DH, bv + DH, br + DH,
      lin2W, lin2b, linW, linb, Wc6, bc768, Wcf, bcf);

  for (int l = 0; l < NL; ++l) {
    if (l == 0) {
      gemm_bf16<<<dim3(MB, 6), blk, 0, stream>>>(
          x_bf, KIN, Wt6, KIN, bias768, qkvp, NPROJ, NN, NPROJ, KIN, 0, 1);
    } else {
      gemm_bf16<<<dim3(MB, 6), blk, 0, stream>>>(
          h2bf, DH, Wc6, DH, bc768, qkvp, NPROJ, NN, NPROJ, DH, 0, 1);
    }

    attn_logits_csr<<<dim3(NB), blk, 0, stream>>>(offsets, csrc, qkvp, s_csr, mb, zb);
    smreduce_kernel<<<dim3(1), dim3(1024), 0, stream>>>(mb, zb, scal + l * 2);
    aggregate_ln_kernel<<<dim3(NB), blk, 0, stream>>>(
        offsets, csrc, cea, s_csr, scal + l * 2, qkvp, ea,
        g1 + (size_t)l * DH, be1 + (size_t)l * DH, ss, ssbf);

    gemm_bf16<<<dim3(MB, 4), blk, 0, stream>>>(
        ssbf, DH, l ? W1t1 : W1t0, DH, b1 + (size_t)l * DFF, ff1bf, DFF, NN, DFF, DH, 1, 1);
    gemm_ff2_ln<<<dim3(MB, 1), blk, 0, stream>>>(
        ff1bf, l ? W2t1 : W2t0, b2 + (size_t)l * DH, ss,
        g2 + (size_t)l * DH, be2 + (size_t)l * DH, h2bf, NN);
  }

  // final: folded (linW @ lin2W) 128 -> 128 + leaky_relu, fp32 out
  gemm_bf16<<<dim3(MB, 1), blk, 0, stream>>>(
      h2bf, DH, Wcf, DH, bcf, out, DH, NN, DH, DH, 2, 0);
}

// Round 7
// 1380.672 us; speedup vs baseline: 1.1658x; 1.0398x over previous
//
#include <hip/hip_runtime.h>
#include <cfloat>
#include <cmath>

#define NN 20000
#define EE 640000
#define DIN 1546
#define KIN 1568   // DIN padded to multiple of 32
#define DH 128
#define DFF 512
#define NL 2
#define NPROJ 768   // q|k|v|r|hi|hj packed columns
#define NB (NN / 4) // node-parallel blocks (4 waves/block, 1 node/wave)

typedef unsigned short ushort_t;
typedef __attribute__((ext_vector_type(8))) short short8;
typedef __attribute__((ext_vector_type(8))) unsigned short ushort8;
typedef __attribute__((ext_vector_type(4))) float floatx4;

__device__ inline ushort_t f2bf(float f) {
  unsigned u = __float_as_uint(f);
  unsigned r = (u + 0x7FFF + ((u >> 16) & 1)) >> 16;
  return (ushort_t)r;
}
__device__ inline float bflo(unsigned u) { return __uint_as_float(u << 16); }
__device__ inline float bfhi(unsigned u) { return __uint_as_float(u & 0xFFFF0000u); }

// ---------------------------------------------------------------------------
// bf16 MFMA GEMM: C[M x N] = act(A[M x K] @ Bt[N x K]^T + bias)
// Reg-staged (harness-proven structure). Bt has exactly gridDim.y*128 rows.
// act: 0 none, 1 relu, 2 leaky(0.01).  out_bf16: 1 -> ushort C, 0 -> float C.
// ---------------------------------------------------------------------------
__global__ __launch_bounds__(256) void gemm_bf16(
    const ushort_t* __restrict__ A, int lda,
    const ushort_t* __restrict__ Bt, int ldb,
    const float* __restrict__ bias, void* __restrict__ Cv, int ldc,
    int M, int Nstore, int K, int act, int out_bf16)
{
  __shared__ ushort_t As[4 * 1032];
  __shared__ ushort_t Bs[4 * 1032];
  const int tid = threadIdx.x;
  const int wave = tid >> 6, lane = tid & 63;
  const int bm = blockIdx.x * 128, bn = blockIdx.y * 128;
  const int wm = (wave >> 1) * 64, wn = (wave & 1) * 64;
  const int frow = lane & 15, kq = lane >> 4;

  floatx4 acc[4][4];
  #pragma unroll
  for (int i = 0; i < 4; ++i)
    #pragma unroll
    for (int j = 0; j < 4; ++j) acc[i][j] = (floatx4){0.f, 0.f, 0.f, 0.f};

  const int srow = tid >> 2, skc = tid & 3;
  const int ar0 = min(bm + srow, M - 1);
  const int ar1 = min(bm + srow + 64, M - 1);
  const ushort_t* Ap0 = A + (size_t)ar0 * lda + skc * 8;
  const ushort_t* Ap1 = A + (size_t)ar1 * lda + skc * 8;
  const ushort_t* Bp0 = Bt + (size_t)(bn + srow) * ldb + skc * 8;
  const ushort_t* Bp1 = Bt + (size_t)(bn + srow + 64) * ldb + skc * 8;
  ushort_t* Aw0 = As + skc * 1032 + srow * 8;
  ushort_t* Aw1 = As + skc * 1032 + (srow + 64) * 8;
  ushort_t* Bw0 = Bs + skc * 1032 + srow * 8;
  ushort_t* Bw1 = Bs + skc * 1032 + (srow + 64) * 8;

  for (int k0 = 0; k0 < K; k0 += 32) {
    ushort8 a0 = *(const ushort8*)Ap0; Ap0 += 32;
    ushort8 a1 = *(const ushort8*)Ap1; Ap1 += 32;
    ushort8 b0 = *(const ushort8*)Bp0; Bp0 += 32;
    ushort8 b1 = *(const ushort8*)Bp1; Bp1 += 32;
    __syncthreads();
    *(ushort8*)Aw0 = a0; *(ushort8*)Aw1 = a1;
    *(ushort8*)Bw0 = b0; *(ushort8*)Bw1 = b1;
    __syncthreads();
    short8 af[4], bfv[4];
    #pragma unroll
    for (int i = 0; i < 4; ++i)
      af[i] = *(const short8*)(As + kq * 1032 + (wm + i * 16 + frow) * 8);
    #pragma unroll
    for (int j = 0; j < 4; ++j)
      bfv[j] = *(const short8*)(Bs + kq * 1032 + (wn + j * 16 + frow) * 8);
    #pragma unroll
    for (int i = 0; i < 4; ++i)
      #pragma unroll
      for (int j = 0; j < 4; ++j)
        acc[i][j] = __builtin_amdgcn_mfma_f32_16x16x32_bf16(af[i], bfv[j], acc[i][j], 0, 0, 0);
  }

  const int rq = (lane >> 4) * 4;
  #pragma unroll
  for (int j = 0; j < 4; ++j) {
    int col = bn + wn + j * 16 + frow;
    if (col >= Nstore) continue;
    float bb = bias ? bias[col] : 0.f;
    #pragma unroll
    for (int i = 0; i < 4; ++i) {
      #pragma unroll
      for (int r = 0; r < 4; ++r) {
        int row = bm + wm + i * 16 + rq + r;
        if (row >= M) continue;
        float v = acc[i][j][r] + bb;
        if (act == 1) v = fmaxf(v, 0.f);
        else if (act == 2) v = v > 0.f ? v : 0.01f * v;
        if (out_bf16) ((ushort_t*)Cv)[(size_t)row * ldc + col] = f2bf(v);
        else          ((float*)Cv)[(size_t)row * ldc + col] = v;
      }
    }
  }
}

// ---------------------------------------------------------------------------
// ff2 GEMM (K=DFF, 128 output cols) with fused LN2: h2 = LN(ss + (A@W2t^T + b2))
// ---------------------------------------------------------------------------
__global__ __launch_bounds__(256) void gemm_ff2_ln(
    const ushort_t* __restrict__ A,          // ff1bf [M][DFF]
    const ushort_t* __restrict__ Bt,         // W2t [DH][DFF]
    const float* __restrict__ bias,          // b2 [DH]
    const float* __restrict__ ss,            // [M][DH] residual input
    const float* __restrict__ g, const float* __restrict__ b,
    ushort_t* __restrict__ Yb, int M)        // h2bf
{
  __shared__ ushort_t As[4 * 1032];
  __shared__ ushort_t Bs[4 * 1032];
  __shared__ float vrow[128][130];
  const int tid = threadIdx.x;
  const int wave = tid >> 6, lane = tid & 63;
  const int bm = blockIdx.x * 128;
  const int wm = (wave >> 1) * 64, wn = (wave & 1) * 64;
  const int frow = lane & 15, kq = lane >> 4;

  floatx4 acc[4][4];
  #pragma unroll
  for (int i = 0; i < 4; ++i)
    #pragma unroll
    for (int j = 0; j < 4; ++j) acc[i][j] = (floatx4){0.f, 0.f, 0.f, 0.f};

  const int srow = tid >> 2, skc = tid & 3;
  const ushort_t* Ap0 = A + (size_t)min(bm + srow, M - 1) * DFF + skc * 8;
  const ushort_t* Ap1 = A + (size_t)min(bm + srow + 64, M - 1) * DFF + skc * 8;
  const ushort_t* Bp0 = Bt + (size_t)srow * DFF + skc * 8;
  const ushort_t* Bp1 = Bt + (size_t)(srow + 64) * DFF + skc * 8;
  ushort_t* Aw0 = As + skc * 1032 + srow * 8;
  ushort_t* Aw1 = As + skc * 1032 + (srow + 64) * 8;
  ushort_t* Bw0 = Bs + skc * 1032 + srow * 8;
  ushort_t* Bw1 = Bs + skc * 1032 + (srow + 64) * 8;

  for (int k0 = 0; k0 < DFF; k0 += 32) {
    ushort8 a0 = *(const ushort8*)Ap0; Ap0 += 32;
    ushort8 a1 = *(const ushort8*)Ap1; Ap1 += 32;
    ushort8 b0 = *(const ushort8*)Bp0; Bp0 += 32;
    ushort8 b1 = *(const ushort8*)Bp1; Bp1 += 32;
    __syncthreads();
    *(ushort8*)Aw0 = a0; *(ushort8*)Aw1 = a1;
    *(ushort8*)Bw0 = b0; *(ushort8*)Bw1 = b1;
    __syncthreads();
    short8 af[4], bfv[4];
    #pragma unroll
    for (int i = 0; i < 4; ++i)
      af[i] = *(const short8*)(As + kq * 1032 + (wm + i * 16 + frow) * 8);
    #pragma unroll
    for (int j = 0; j < 4; ++j)
      bfv[j] = *(const short8*)(Bs + kq * 1032 + (wn + j * 16 + frow) * 8);
    #pragma unroll
    for (int i = 0; i < 4; ++i)
      #pragma unroll
      for (int j = 0; j < 4; ++j)
        acc[i][j] = __builtin_amdgcn_mfma_f32_16x16x32_bf16(af[i], bfv[j], acc[i][j], 0, 0, 0);
  }

  const int rq = (lane >> 4) * 4;
  #pragma unroll
  for (int j = 0; j < 4; ++j) {
    int col = wn + j * 16 + frow;
    float bb = bias[col];
    #pragma unroll
    for (int i = 0; i < 4; ++i) {
      #pragma unroll
      for (int r = 0; r < 4; ++r) {
        int row = wm + i * 16 + rq + r;
        int grow = bm + row;
        float v = acc[i][j][r] + bb;
        if (grow < M) v += ss[(size_t)grow * DH + col];
        vrow[row][col] = v;
      }
    }
  }
  __syncthreads();

  float2 gg = *(const float2*)(g + lane * 2);
  float2 bbv = *(const float2*)(b + lane * 2);
  for (int rr = 0; rr < 32; ++rr) {
    int row = wave * 32 + rr;
    int grow = bm + row;
    if (grow >= M) break;
    float x0 = vrow[row][lane * 2], x1 = vrow[row][lane * 2 + 1];
    float s = x0 + x1;
    #pragma unroll
    for (int m = 32; m >= 1; m >>= 1) s += __shfl_xor(s, m);
    float mean = s * (1.f / 128.f);
    float dx = x0 - mean, dy = x1 - mean;
    float v = dx * dx + dy * dy;
    #pragma unroll
    for (int m = 32; m >= 1; m >>= 1) v += __shfl_xor(v, m);
    float rstd = rsqrtf(v * (1.f / 128.f) + 1e-5f);
    float o0 = dx * rstd * gg.x + bbv.x;
    float o1 = dy * rstd * gg.y + bbv.y;
    ushort_t* pp = Yb + (size_t)grow * DH + lane * 2;
    pp[0] = f2bf(o0); pp[1] = f2bf(o1);
  }
}

// ---------------------------------------------------------------------------
// Pack / convert kernels
// ---------------------------------------------------------------------------
__global__ __launch_bounds__(256) void convert_x_kernel(
    const float* __restrict__ x, ushort_t* __restrict__ xb)
{
  const unsigned CPR = KIN / 8;  // 196 chunks per row
  unsigned gid = blockIdx.x * 256 + threadIdx.x;
  if (gid >= (unsigned)NN * CPR) return;
  unsigned row = gid / CPR;
  unsigned c8 = (gid - row * CPR) * 8;
  const float* xr = x + (size_t)row * DIN;
  ushort8 o;
  #pragma unroll
  for (int j = 0; j < 8; ++j)
    o[j] = (c8 + j < DIN) ? f2bf(xr[c8 + j]) : (ushort_t)0;
  *(ushort8*)(xb + (size_t)row * KIN + c8) = o;
}

// tiled-transpose pack of the 6 layer-0 projection weights
__global__ __launch_bounds__(256) void pack6t_kernel(
    const float* __restrict__ Wq, const float* __restrict__ Wk,
    const float* __restrict__ Wv, const float* __restrict__ Wr,
    const float* __restrict__ Whi, const float* __restrict__ Whj,
    ushort_t* __restrict__ Wt6)
{
  __shared__ float tile[32][33];
  const int k0 = blockIdx.x * 32;   // 49 -> 1568
  const int n0 = blockIdx.y * 32;   // 24 -> 768
  const float* Ws[6] = {Wq, Wk, Wv, Wr, Whi, Whj};
  const float* W = Ws[n0 >> 7];
  const int c0 = n0 & 127;
  const int tc = threadIdx.x & 31, tr = threadIdx.x >> 5;
  #pragma unroll
  for (int r = tr; r < 32; r += 8) {
    int k = k0 + r;
    tile[r][tc] = (k < DIN) ? W[(size_t)k * DH + c0 + tc] : 0.f;
  }
  __syncthreads();
  #pragma unroll
  for (int n = tr; n < 32; n += 8)
    Wt6[(size_t)(n0 + n) * KIN + k0 + tc] = f2bf(tile[tc][n]);
}

// one kernel packs W1t/W2t for BOTH layers + bias768 (layer 0).
__global__ void pack_small_kernel(
    const float* __restrict__ W1, const float* __restrict__ W2,
    const float* __restrict__ bq, const float* __restrict__ bk,
    const float* __restrict__ bv, const float* __restrict__ br,
    ushort_t* __restrict__ W1t0, ushort_t* __restrict__ W1t1,
    ushort_t* __restrict__ W2t0, ushort_t* __restrict__ W2t1,
    float* __restrict__ bias768)
{
  const int y = blockIdx.y;
  const int tid = threadIdx.x;
  if (y < 1024) {                     // W1t[l][n][k] = W1[l][k][n], k<DH
    int l = y >> 9, n = y & 511;
    const float* src = W1 + (size_t)l * DH * DFF;
    ushort_t* dst = l ? W1t1 : W1t0;
    if (tid < DH) dst[(size_t)n * DH + tid] = f2bf(src[(size_t)tid * DFF + n]);
  } else if (y < 1280) {              // W2t[l][n][k] = W2[l][k][n], k<DFF
    int l = (y - 1024) >> 7, n = (y - 1024) & 127;
    const float* src = W2 + (size_t)l * DFF * DH;
    ushort_t* dst = l ? W2t1 : W2t0;
    for (int k = tid; k < DFF; k += 256)
      dst[(size_t)n * DFF + k] = f2bf(src[(size_t)k * DH + n]);
  } else {
    int n = (y - 1280) * 256 + tid;
    if (n < NPROJ) {
      int which = n >> 7, c = n & 127;
      float v = 0.f;
      if (which == 0) v = bq[c]; else if (which == 1) v = bk[c];
      else if (which == 2) v = bv[c]; else if (which == 3) v = br[c];
      bias768[n] = v;
    }
  }
}

// ---------------------------------------------------------------------------
// Weight folding: x @ W + b == h @ (linW @ W) + (linb @ W + b), exact f32.
// blocks [0,384): 6-proj fold -> Wc6/bc768; [384,448): lin2 fold -> Wcf/bcf.
// ---------------------------------------------------------------------------
__global__ __launch_bounds__(256) void combine_all_kernel(
    const float* __restrict__ Wq, const float* __restrict__ Wk,
    const float* __restrict__ Wv, const float* __restrict__ Wr,
    const float* __restrict__ Whi, const float* __restrict__ Whj,
    const float* __restrict__ bq, const float* __restrict__ bk,
    const float* __restrict__ bv, const float* __restrict__ br,
    const float* __restrict__ lin2W, const float* __restrict__ lin2b,
    const float* __restrict__ linW, const float* __restrict__ linb,
    ushort_t* __restrict__ Pc, float* __restrict__ bc,
    ushort_t* __restrict__ Pf, float* __restrict__ bf_out)
{
  const int j = threadIdx.x >> 7;
  const int k = threadIdx.x & 127;
  const bool six = blockIdx.x < (NPROJ / 2);
  const int n = six ? blockIdx.x * 2 + j : (blockIdx.x - NPROJ / 2) * 2 + j;
  const float* Ws[6] = {Wq, Wk, Wv, Wr, Whi, Whj};
  const float* W = six ? Ws[n >> 7] : lin2W;
  const int col = six ? (n & 127) : n;
  __shared__ float wcol[2][DIN];
  for (int d = k; d < DIN; d += 128)
    wcol[j][d] = W[(size_t)d * DH + col];
  __syncthreads();
  const float* lr = linW + (size_t)k * DIN;
  float acc = 0.f;
  #pragma unroll 4
  for (int d = 0; d < DIN; d += 2) {
    float2 lv = *(const float2*)(lr + d);
    acc = fmaf(wcol[j][d], lv.x, acc);
    acc = fmaf(wcol[j][d + 1], lv.y, acc);
  }
  if (six) Pc[(size_t)n * DH + k] = f2bf(acc);
  else     Pf[(size_t)n * DH + k] = f2bf(acc);
  float bs = 0.f;
  for (int d = k; d < DIN; d += 128) bs += linb[d] * wcol[j][d];
  #pragma unroll
  for (int m = 32; m >= 1; m >>= 1) bs += __shfl_xor(bs, m);
  __shared__ float red[4];
  if ((threadIdx.x & 63) == 0) red[threadIdx.x >> 6] = bs;
  __syncthreads();
  if (k == 0) {
    float tot = red[j * 2] + red[j * 2 + 1];
    if (six) {
      int which = n >> 7, c = n & 127;
      float b0 = 0.f;
      if (which == 0) b0 = bq[c]; else if (which == 1) b0 = bk[c];
      else if (which == 2) b0 = bv[c]; else if (which == 3) b0 = br[c];
      bc[n] = b0 + tot;
    } else {
      bf_out[n] = lin2b[n] + tot;
    }
  }
}

// ---------------------------------------------------------------------------
// CSR build (csrc[pos]=src node, cea[pos]=edge id)
// ---------------------------------------------------------------------------
__global__ void hist_kernel(const int* __restrict__ ei, int* __restrict__ counts) {
  int e = blockIdx.x * 256 + threadIdx.x;
  if (e < EE) atomicAdd(&counts[ei[EE + e]], 1);
}

__global__ __launch_bounds__(1024) void scan_kernel(const int* __restrict__ counts,
                                                    int* __restrict__ offsets,
                                                    int* __restrict__ cursor) {
  __shared__ int sums[1024];
  const int t = threadIdx.x;
  const int PER = 20;
  int base = t * PER;
  int loc[PER]; int s = 0;
  #pragma unroll
  for (int i = 0; i < PER; ++i) {
    int idx = base + i;
    int c = (idx < NN) ? counts[idx] : 0;
    loc[i] = s; s += c;
  }
  sums[t] = s;
  __syncthreads();
  for (int d = 1; d < 1024; d <<= 1) {
    int v = (t >= d) ? sums[t - d] : 0;
    __syncthreads();
    sums[t] += v;
    __syncthreads();
  }
  int pre = (t > 0) ? sums[t - 1] : 0;
  #pragma unroll
  for (int i = 0; i < PER; ++i) {
    int idx = base + i;
    if (idx < NN) { offsets[idx] = pre + loc[i]; cursor[idx] = pre + loc[i]; }
  }
  if (t == 0) offsets[NN] = sums[1023];
}

__global__ void scatter_kernel(const int* __restrict__ ei, int* __restrict__ cursor,
                               int* __restrict__ csrc, int* __restrict__ cea) {
  int e = blockIdx.x * 256 + threadIdx.x;
  if (e < EE) {
    int src = ei[e];
    int p = atomicAdd(&cursor[ei[EE + e]], 1);
    csrc[p] = src;
    cea[p] = e;
  }
}

// ---------------------------------------------------------------------------
// FUSED edge pass: per node, single traversal computing per-node online
// softmax (m_i, z_i) AND unnormalized gated aggregate
//   A_i[c] = sum_e exp(s_e - m_i) * v[src][c] * gate_e[c].
// Loop structure = R5's proven shape: two half-waves walk t = hh, hh+2, ...;
// every lane in a half loads csrc[pos]/cea[pos] directly (broadcast load);
// all cross-lane ops are shfl_xor <= 16 (stay inside the half).
// Global result later: aggr = exp(m_i - M)/Z * A_i (scale_ln_kernel).
// ---------------------------------------------------------------------------
__global__ __launch_bounds__(256) void edge_fused_kernel(
    const int* __restrict__ offsets, const int* __restrict__ csrc,
    const int* __restrict__ cea, const ushort_t* __restrict__ qkv,
    const float* __restrict__ ea,
    float* __restrict__ Abuf, float* __restrict__ mnode,
    float* __restrict__ mb, float* __restrict__ zb)
{
  const int wid = threadIdx.x >> 6;
  const int node = blockIdx.x * 4 + wid;
  const int lane = threadIdx.x & 63;
  const int sub = lane & 31, hh = lane >> 5;
  float m = -FLT_MAX, z = 0.f;
  float a0 = 0.f, a1 = 0.f, a2 = 0.f, a3 = 0.f;

  const int off = offsets[node];
  const int deg = offsets[node + 1] - off;
  const ushort_t* bd = qkv + (size_t)node * NPROJ;
  uint2 qu = *(const uint2*)(bd + sub * 4);
  const float q0 = bflo(qu.x), q1 = bfhi(qu.x), q2 = bflo(qu.y), q3 = bfhi(qu.y);
  uint2 hjv = *(const uint2*)(bd + 640 + sub * 4);
  const float hj0 = bflo(hjv.x), hj1 = bfhi(hjv.x), hj2 = bflo(hjv.y), hj3 = bfhi(hjv.y);

  for (int t = hh; t < deg; t += 2) {
    int pos = off + t;
    int src = csrc[pos];    // uniform within the half -> broadcast load
    int e   = cea[pos];
    const ushort_t* bs = qkv + (size_t)src * NPROJ;
    uint2 ku = *(const uint2*)(bs + DH  + sub * 4);
    uint2 vu = *(const uint2*)(bs + 256 + sub * 4);
    uint2 hu = *(const uint2*)(bs + 512 + sub * 4);
    float4 ev = *(const float4*)(ea + (size_t)e * DH + sub * 4);
    float d = q0 * bflo(ku.x) + q1 * bfhi(ku.x) + q2 * bflo(ku.y) + q3 * bfhi(ku.y);
    #pragma unroll
    for (int mm = 16; mm >= 1; mm >>= 1) d += __shfl_xor(d, mm);
    // branch-free online-softmax update
    float mn = fmaxf(m, d);
    float sc = __expf(m - mn);   // 1 when m stays
    float w  = __expf(d - mn);
    z = z * sc + w;
    a0 *= sc; a1 *= sc; a2 *= sc; a3 *= sc;
    m = mn;
    float g0 = 1.f / (1.f + __expf(-(ev.x + bflo(hu.x) + hj0)));
    float g1 = 1.f / (1.f + __expf(-(ev.y + bfhi(hu.x) + hj1)));
    float g2v = 1.f / (1.f + __expf(-(ev.z + bflo(hu.y) + hj2)));
    float g3 = 1.f / (1.f + __expf(-(ev.w + bfhi(hu.y) + hj3)));
    a0 = fmaf(w * bflo(vu.x), g0, a0);
    a1 = fmaf(w * bfhi(vu.x), g1, a1);
    a2 = fmaf(w * bflo(vu.y), g2v, a2);
    a3 = fmaf(w * bfhi(vu.y), g3, a3);
  }
  // merge the two halves (exp-weighted; underflow handles empty halves)
  {
    float mo = __shfl_xor(m, 32), zo = __shfl_xor(z, 32);
    float b0o = __shfl_xor(a0, 32), b1o = __shfl_xor(a1, 32);
    float b2o = __shfl_xor(a2, 32), b3o = __shfl_xor(a3, 32);
    float mn = fmaxf(m, mo);
    float ws = __expf(m - mn), wo = __expf(mo - mn);
    a0 = a0 * ws + b0o * wo; a1 = a1 * ws + b1o * wo;
    a2 = a2 * ws + b2o * wo; a3 = a3 * ws + b3o * wo;
    z = z * ws + zo * wo;
    m = mn;
  }
  if (hh == 0) {
    *(float4*)(Abuf + (size_t)node * DH + sub * 4) = make_float4(a0, a1, a2, a3);
    if (sub == 0) mnode[node] = m;
  }
  __shared__ float ms[4], zs[4];
  if (lane == 0) { ms[wid] = m; zs[wid] = z; }
  __syncthreads();
  if (threadIdx.x == 0) {
    float M4 = fmaxf(fmaxf(ms[0], ms[1]), fmaxf(ms[2], ms[3]));
    float Z4 = zs[0] * __expf(ms[0] - M4) + zs[1] * __expf(ms[1] - M4)
             + zs[2] * __expf(ms[2] - M4) + zs[3] * __expf(ms[3] - M4);
    mb[blockIdx.x] = M4; zb[blockIdx.x] = Z4;
  }
}

// merge NB (m,Z) pairs -> scal[0]=M, scal[1]=Z  (single block)
__global__ __launch_bounds__(1024) void smreduce_kernel(
    const float* __restrict__ mb, const float* __restrict__ zb,
    float* __restrict__ scal)
{
  const int t = threadIdx.x;
  float m = -FLT_MAX, z = 0.f;
  for (int i = t; i < NB; i += 1024) {
    float mi = mb[i], zi = zb[i];
    float mn = fmaxf(m, mi);
    z = z * __expf(m - mn) + zi * __expf(mi - mn);
    m = mn;
  }
  #pragma unroll
  for (int s = 32; s >= 1; s >>= 1) {
    float mo = __shfl_xor(m, s), zo = __shfl_xor(z, s);
    float mn = fmaxf(m, mo);
    z = z * __expf(m - mn) + zo * __expf(mo - mn);
    m = mn;
  }
  __shared__ float ms[16], zs[16];
  if ((t & 63) == 0) { ms[t >> 6] = m; zs[t >> 6] = z; }
  __syncthreads();
  if (t == 0) {
    float M = ms[0], Z = zs[0];
    for (int i = 1; i < 16; ++i) {
      float mn = fmaxf(M, ms[i]);
      Z = Z * __expf(M - mn) + zs[i] * __expf(ms[i] - mn);
      M = mn;
    }
    scal[0] = M; scal[1] = Z;
  }
}

// ---------------------------------------------------------------------------
// Final per-node scale + root + LN1: a = r + exp(m_i - M)/Z * A; ss = LN(a)
// ---------------------------------------------------------------------------
__global__ __launch_bounds__(256) void scale_ln_kernel(
    const float* __restrict__ Abuf, const float* __restrict__ mnode,
    const float* __restrict__ scal, const ushort_t* __restrict__ qkv,
    const float* __restrict__ g, const float* __restrict__ b,
    float* __restrict__ ss, ushort_t* __restrict__ ssbf)
{
  const int node = blockIdx.x * 4 + (threadIdx.x >> 6);
  const int lane = threadIdx.x & 63;
  if (node >= NN) return;
  const float M = scal[0];
  const float invZ = 1.f / scal[1];
  const float gam = __expf(mnode[node] - M) * invZ;
  float2 A = *(const float2*)(Abuf + (size_t)node * DH + lane * 2);
  unsigned rp = *(const unsigned*)(qkv + (size_t)node * NPROJ + 384 + lane * 2);
  float a0 = fmaf(gam, A.x, bflo(rp));
  float a1 = fmaf(gam, A.y, bfhi(rp));
  float s = a0 + a1;
  #pragma unroll
  for (int m = 32; m >= 1; m >>= 1) s += __shfl_xor(s, m);
  float mean = s * (1.f / 128.f);
  float dx = a0 - mean, dy = a1 - mean;
  float v = dx * dx + dy * dy;
  #pragma unroll
  for (int m = 32; m >= 1; m >>= 1) v += __shfl_xor(v, m);
  float rstd = rsqrtf(v * (1.f / 128.f) + 1e-5f);
  float2 gg = *(const float2*)(g + lane * 2);
  float2 bb = *(const float2*)(b + lane * 2);
  float o0 = dx * rstd * gg.x + bb.x;
  float o1 = dy * rstd * gg.y + bb.y;
  *(float2*)(ss + (size_t)node * DH + lane * 2) = make_float2(o0, o1);
  ushort_t* pp = ssbf + (size_t)node * DH + lane * 2;
  pp[0] = f2bf(o0); pp[1] = f2bf(o1);
}

// ---------------------------------------------------------------------------
extern "C" void kernel_launch(void* const* d_in, const int* in_sizes, int n_in,
                              void* d_out, int out_size, void* d_ws, size_t ws_size,
                              hipStream_t stream)
{
  const float* x_in  = (const float*)d_in[0];
  const int*   ei    = (const int*)d_in[1];
  const float* ea    = (const float*)d_in[2];
  const float* Wq    = (const float*)d_in[3];
  const float* bq    = (const float*)d_in[4];
  const float* Wk    = (const float*)d_in[5];
  const float* bk    = (const float*)d_in[6];
  const float* Wv    = (const float*)d_in[7];
  const float* bv    = (const float*)d_in[8];
  const float* Wr    = (const float*)d_in[9];
  const float* br    = (const float*)d_in[10];
  const float* Whi   = (const float*)d_in[11];
  const float* Whj   = (const float*)d_in[12];
  const float* W1    = (const float*)d_in[13];
  const float* b1    = (const float*)d_in[14];
  const float* W2    = (const float*)d_in[15];
  const float* b2    = (const float*)d_in[16];
  const float* g1    = (const float*)d_in[17];
  const float* be1   = (const float*)d_in[18];
  const float* g2    = (const float*)d_in[19];
  const float* be2   = (const float*)d_in[20];
  const float* linW  = (const float*)d_in[21];
  const float* linb  = (const float*)d_in[22];
  const float* lin2W = (const float*)d_in[23];
  const float* lin2b = (const float*)d_in[24];
  float* out = (float*)d_out;

  char* p = (char*)d_ws;
  auto alloc = [&](size_t bytes) -> void* {
    void* r = (void*)p; p += (bytes + 63) & ~((size_t)63); return r;
  };
  ushort_t* x_bf   = (ushort_t*)alloc((size_t)NN * KIN * 2);
  ushort_t* qkvp   = (ushort_t*)alloc((size_t)NN * NPROJ * 2);
  ushort_t* Wt6    = (ushort_t*)alloc((size_t)NPROJ * KIN * 2);
  ushort_t* W1t0   = (ushort_t*)alloc((size_t)DFF * DH * 2);
  ushort_t* W1t1   = (ushort_t*)alloc((size_t)DFF * DH * 2);
  ushort_t* W2t0   = (ushort_t*)alloc((size_t)DH * DFF * 2);
  ushort_t* W2t1   = (ushort_t*)alloc((size_t)DH * DFF * 2);
  ushort_t* Wc6    = (ushort_t*)alloc((size_t)NPROJ * DH * 2);  // folded layer-1 proj
  ushort_t* Wcf    = (ushort_t*)alloc((size_t)DH * DH * 2);     // folded final linear
  float*    bias768= (float*)alloc(NPROJ * 4);
  float*    bc768  = (float*)alloc(NPROJ * 4);
  float*    bcf    = (float*)alloc(DH * 4);
  float*    scal   = (float*)alloc(64);
  int*      counts = (int*)alloc((size_t)NN * 4);
  int*      offsets= (int*)alloc((size_t)(NN + 1) * 4);
  int*      cursor = (int*)alloc((size_t)NN * 4);
  int*      csrc   = (int*)alloc((size_t)EE * 4);
  int*      cea    = (int*)alloc((size_t)EE * 4);
  float*    mb     = (float*)alloc((size_t)NB * 4);
  float*    zb     = (float*)alloc((size_t)NB * 4);
  float*    Abuf   = (float*)alloc((size_t)NN * DH * 4);
  float*    mnode  = (float*)alloc((size_t)NN * 4);
  float*    ss     = (float*)alloc((size_t)NN * DH * 4);
  ushort_t* ssbf   = (ushort_t*)alloc((size_t)NN * DH * 2);
  ushort_t* ff1bf  = (ushort_t*)alloc((size_t)NN * DFF * 2);
  ushort_t* h2bf   = (ushort_t*)alloc((size_t)NN * DH * 2);

  const dim3 blk(256);
  const int MB = (NN + 127) / 128;  // 157

  // --- setup ---
  convert_x_kernel<<<dim3((NN * (KIN / 8) + 255) / 256), blk, 0, stream>>>(x_in, x_bf);
  hipMemsetAsync(counts, 0, (size_t)NN * 4, stream);
  hist_kernel<<<dim3(EE / 256), blk, 0, stream>>>(ei, counts);
  scan_kernel<<<dim3(1), dim3(1024), 0, stream>>>(counts, offsets, cursor);
  scatter_kernel<<<dim3(EE / 256), blk, 0, stream>>>(ei, cursor, csrc, cea);
  pack6t_kernel<<<dim3(KIN / 32, NPROJ / 32), blk, 0, stream>>>(
      Wq, Wk, Wv, Wr, Whi, Whj, Wt6);
  pack_small_kernel<<<dim3(1, 1283), blk, 0, stream>>>(
      W1, W2, bq, bk, bv, br, W1t0, W1t1, W2t0, W2t1, bias768);
  const size_t wo1 = (size_t)DIN * DH;
  combine_all_kernel<<<dim3(NPROJ / 2 + DH / 2), blk, 0, stream>>>(
      Wq + wo1, Wk + wo1, Wv + wo1, Wr + wo1, Whi + wo1, Whj + wo1,
      bq + DH, bk + DH, bv + DH, br + DH,
      lin2W, lin2b, linW, linb, Wc6, bc768, Wcf, bcf);

  for (int l = 0; l < NL; ++l) {
    if (l == 0) {
      gemm_bf16<<<dim3(MB, 6), blk, 0, stream>>>(
          x_bf, KIN, Wt6, KIN, bias768, qkvp, NPROJ, NN, NPROJ, KIN, 0, 1);
    } else {
      gemm_bf16<<<dim3(MB, 6), blk, 0, stream>>>(
          h2bf, DH, Wc6, DH, bc768, qkvp, NPROJ, NN, NPROJ, DH, 0, 1);
    }

    // single-pass edge processing (logits + online softmax + gated aggregate)
    edge_fused_kernel<<<dim3(NB), blk, 0, stream>>>(
        offsets, csrc, cea, qkvp, ea, Abuf, mnode, mb, zb);
    smreduce_kernel<<<dim3(1), dim3(1024), 0, stream>>>(mb, zb, scal + l * 2);
    scale_ln_kernel<<<dim3(NB), blk, 0, stream>>>(
        Abuf, mnode, scal + l * 2, qkvp,
        g1 + (size_t)l * DH, be1 + (size_t)l * DH, ss, ssbf);

    gemm_bf16<<<dim3(MB, 4), blk, 0, stream>>>(
        ssbf, DH, l ? W1t1 : W1t0, DH, b1 + (size_t)l * DFF, ff1bf, DFF, NN, DFF, DH, 1, 1);
    gemm_ff2_ln<<<dim3(MB, 1), blk, 0, stream>>>(
        ff1bf, l ? W2t1 : W2t0, b2 + (size_t)l * DH, ss,
        g2 + (size_t)l * DH, be2 + (size_t)l * DH, h2bf, NN);
  }

  // final: folded (linW @ lin2W) 128 -> 128 + leaky_relu, fp32 out
  gemm_bf16<<<dim3(MB, 1), blk, 0, stream>>>(
      h2bf, DH, Wcf, DH, bcf, out, DH, NN, DH, DH, 2, 0);
}